// Round 3
// baseline (460.296 us; speedup 1.0000x reference)
//
#include <hip/hip_runtime.h>

typedef __bf16 bf16_t;
typedef bf16_t bf16x8 __attribute__((ext_vector_type(8)));
typedef float f32x4 __attribute__((ext_vector_type(4)));

#define MFMA16(a, b, c) __builtin_amdgcn_mfma_f32_16x16x32_bf16(a, b, c, 0, 0, 0)

__device__ __forceinline__ unsigned short f2bf(float f) {
    union { float f; unsigned u; } v; v.f = f;
    unsigned r = v.u + 0x7FFFu + ((v.u >> 16) & 1u);  // RNE
    return (unsigned short)(r >> 16);
}
__device__ __forceinline__ float bf2f(unsigned short h) {
    union { unsigned u; float f; } v; v.u = ((unsigned)h) << 16;
    return v.f;
}
__device__ __forceinline__ unsigned short to_bf(float f) {
    bf16_t b = (bf16_t)f;                 // gfx950 native v_cvt (RNE)
    return __builtin_bit_cast(unsigned short, b);
}

// async global->LDS, 16B per lane; LDS dst is wave-uniform base + lane*16
__device__ __forceinline__ void gll16(const unsigned short* g, unsigned short* l) {
    __builtin_amdgcn_global_load_lds(
        (const __attribute__((address_space(1))) unsigned int*)g,
        (__attribute__((address_space(3))) unsigned int*)l, 16, 0, 0);
}

// ---------------- cast kernels ----------------
__global__ __launch_bounds__(256) void cast_x_kernel(const float* __restrict__ src,
                                                     unsigned short* __restrict__ dst, int n) {
    int i = (blockIdx.x * 256 + threadIdx.x) * 4;
    if (i >= n) return;
    float4 v = *(const float4*)&src[i];
    union { unsigned short e[4]; uint2 u; } p;
    p.e[0] = f2bf(v.x); p.e[1] = f2bf(v.y); p.e[2] = f2bf(v.z); p.e[3] = f2bf(v.w);
    *(uint2*)&dst[i] = p.u;
}

// src is K x N row-major fp32 (K=2048); dst is N x K row-major bf16 (B^T).
// LDS-tiled 64x64 transpose: coalesced reads AND writes.
__global__ __launch_bounds__(256) void castT_kernel(const float* __restrict__ src,
                                                    unsigned short* __restrict__ dst,
                                                    int N) {
    __shared__ __align__(16) unsigned short sT[64 * 68];
    int nt = blockIdx.x >> 5;            // K/64 == 32 (K fixed at 2048)
    int kt = blockIdx.x & 31;
    int k0 = kt * 64, n0 = nt * 64;
    int t = threadIdx.x;
#pragma unroll
    for (int c = t; c < 1024; c += 256) {
        int r = c >> 4, c4 = c & 15;
        float4 v = *(const float4*)&src[(size_t)(k0 + r) * N + n0 + c4 * 4];
        union { unsigned short e[4]; uint2 u; } p;
        p.e[0] = f2bf(v.x); p.e[1] = f2bf(v.y); p.e[2] = f2bf(v.z); p.e[3] = f2bf(v.w);
        *(uint2*)&sT[r * 68 + c4 * 4] = p.u;   // sT[k-row][n-col]
    }
    __syncthreads();
#pragma unroll
    for (int c = t; c < 512; c += 256) {
        int n = c >> 3, cb = c & 7;
        union { unsigned short e[8]; uint4 v; } u;
#pragma unroll
        for (int j = 0; j < 8; ++j) u.e[j] = sT[(cb * 8 + j) * 68 + n];
        *(uint4*)&dst[(size_t)(n0 + n) * 2048 + k0 + cb * 8] = u.v;
    }
}

// ---------------- GEMM: C(MxN) = A(MxK,bf16) * Bt(NxK,bf16)^T ----------------
// m97 structure: global_load_lds width=16 staging, unpadded stride-64 LDS.
__global__ __launch_bounds__(256) void gemm_bt(
    const unsigned short* __restrict__ A,
    const unsigned short* __restrict__ Bt,
    float* __restrict__ Cf, unsigned short* __restrict__ Cb,
    int M, int N, int K)
{
    __shared__ __align__(16) unsigned short sA[128 * 64];
    __shared__ __align__(16) unsigned short sB[128 * 64];
    int n0 = blockIdx.x * 128, m0 = blockIdx.y * 128;
    int tid = threadIdx.x;
    int lane = tid & 63, w = tid >> 6;
    int wm = (w >> 1) * 64, wn = (w & 1) * 64;
    int lo = lane & 15, quad = lane >> 4;

    // wave w stages rows [w*32, w*32+32): 4 chunks of 8 rows x 64 cols (1024 B)
    int srow = w * 32 + (lane >> 3);
    int scol = (lane & 7) * 8;
    const unsigned short* Ag = &A[(size_t)(m0 + srow) * K + scol];
    const unsigned short* Bg = &Bt[(size_t)(n0 + srow) * K + scol];

    f32x4 acc[4][4];
#pragma unroll
    for (int i = 0; i < 4; ++i)
#pragma unroll
        for (int j = 0; j < 4; ++j) acc[i][j] = (f32x4){0.f, 0.f, 0.f, 0.f};

    for (int kt = 0; kt < K; kt += 64) {
#pragma unroll
        for (int c = 0; c < 4; ++c) {
            gll16(Ag + (size_t)(c * 8) * K + kt, &sA[(w * 4 + c) * 512]);
            gll16(Bg + (size_t)(c * 8) * K + kt, &sB[(w * 4 + c) * 512]);
        }
        __syncthreads();
#pragma unroll
        for (int ks = 0; ks < 64; ks += 32) {
            bf16x8 af[4], bfr[4];
#pragma unroll
            for (int mi = 0; mi < 4; ++mi)
                af[mi] = *(const bf16x8*)&sA[(wm + mi * 16 + lo) * 64 + ks + quad * 8];
#pragma unroll
            for (int ni = 0; ni < 4; ++ni)
                bfr[ni] = *(const bf16x8*)&sB[(wn + ni * 16 + lo) * 64 + ks + quad * 8];
#pragma unroll
            for (int mi = 0; mi < 4; ++mi)
#pragma unroll
                for (int ni = 0; ni < 4; ++ni)
                    acc[mi][ni] = MFMA16(af[mi], bfr[ni], acc[mi][ni]);
        }
        __syncthreads();
    }

#pragma unroll
    for (int mi = 0; mi < 4; ++mi)
#pragma unroll
        for (int ni = 0; ni < 4; ++ni)
#pragma unroll
            for (int r = 0; r < 4; ++r) {
                int row = m0 + wm + mi * 16 + quad * 4 + r;
                int col = n0 + wn + ni * 16 + lo;
                if (Cf) Cf[(size_t)row * N + col] = acc[mi][ni][r];
                else    Cb[(size_t)row * N + col] = f2bf(acc[mi][ni][r]);
            }
}

// ---------------- RMSNorm + RoPE (+ scatter to outputs) ----------------
// qkv: (B*S, 3072) bf16 rows = [q 2048 | k 512 | v 512]
__global__ __launch_bounds__(256) void rmsrope_kernel(
    const unsigned short* __restrict__ qkv,
    const float* __restrict__ cosb, const float* __restrict__ sinb,
    const float* __restrict__ q_scale, const float* __restrict__ k_scale,
    unsigned short* __restrict__ q_attn, unsigned short* __restrict__ k_attn,
    float* __restrict__ k_out, float* __restrict__ v_out)
{
    int wid = blockIdx.x * 4 + (threadIdx.x >> 6);   // one wave per 64-elem row
    int lane = threadIdx.x & 63;
    int t = wid % 48;          // 0..31 q-head, 32..39 k-group, 40..47 v-group
    int bs = wid / 48;         // 0..4095
    int b = bs >> 11, s = bs & 2047;

    if (t >= 40) {             // v: straight copy to output (b,g,s,d) fp32
        int g = t - 40;
        float val = bf2f(qkv[(size_t)bs * 3072 + 2560 + g * 64 + lane]);
        v_out[(size_t)((b * 8 + g) * 2048 + s) * 64 + lane] = val;
        return;
    }
    bool is_q = (t < 32);
    int col = is_q ? (t * 64) : (2048 + (t - 32) * 64);
    float val = bf2f(qkv[(size_t)bs * 3072 + col + lane]);
    float ss = val * val;
#pragma unroll
    for (int m = 1; m < 64; m <<= 1) ss += __shfl_xor(ss, m);
    float rs = rsqrtf(ss * (1.0f / 64.0f) + 1e-6f);
    float scl = is_q ? q_scale[lane] : k_scale[lane];
    float xn = val * rs * scl;
    float other = __shfl_xor(xn, 32);
    float rot = (lane < 32) ? -other : other;     // [-x2, x1]
    float o = xn * cosb[s * 64 + lane] + rot * sinb[s * 64 + lane];
    if (is_q) {
        // fold 1/sqrt(D)=0.125 and log2(e) into q (attention works in exp2 domain)
        q_attn[(size_t)((b * 32 + t) * 2048 + s) * 64 + lane] = to_bf(o * (0.125f * 1.44269504f));
    } else {
        int g = t - 32;
        size_t idx = (size_t)((b * 8 + g) * 2048 + s) * 64 + lane;
        k_attn[idx] = to_bf(o);
        k_out[idx] = o;
    }
}

// ---------------- V transpose: qkv v-cols -> vt (b,g,d,s) bf16 ----------------
__global__ __launch_bounds__(256) void vtrans_kernel(
    const unsigned short* __restrict__ qkv, unsigned short* __restrict__ vt)
{
    __shared__ __align__(16) unsigned short sT[64 * 68];
    int idx = blockIdx.x;            // B*G*32 = 512
    int st = idx & 31, g = (idx >> 5) & 7, b = idx >> 8;
    int tid = threadIdx.x;
#pragma unroll
    for (int c = tid; c < 512; c += 256) {
        int r = c >> 3, cb = c & 7;
        *(uint4*)&sT[r * 68 + cb * 8] =
            *(const uint4*)&qkv[(size_t)(b * 2048 + st * 64 + r) * 3072 + 2560 + g * 64 + cb * 8];
    }
    __syncthreads();
#pragma unroll
    for (int c = tid; c < 512; c += 256) {
        int d = c >> 3, cb = c & 7;
        union { unsigned short e[8]; uint4 v; } u;
#pragma unroll
        for (int j = 0; j < 8; ++j) u.e[j] = sT[(cb * 8 + j) * 68 + d];
        *(uint4*)&vt[((size_t)(b * 8 + g) * 64 + d) * 2048 + st * 64 + cb * 8] = u.v;
    }
}

// ---------------- flash attention, causal, GQA ----------------
// R2 post-mortem: occupancy was grid-limited — the (b,h,pair) decomposition
// only yields 2048 wave-tasks = 8 waves/CU. This version creates 4096 uniform
// wave-tasks by splitting each pair-task along the KV axis (exact: no running
// max => softmax partials (o,l) are additive over disjoint kv ranges):
//   wave X: big tile 63-p, kt in [0,15]            -> 16 iterations
//   wave Y: small tile p fully (owns its output) +
//           big-tile tail kt in [16, ktmax(63-p)]  -> 17 iterations (all p)
// Block = 8 waves = {X,Y} x 4 heads of one (b,g,p): 512 blocks x 8 waves =
// 4096 waves = 16 waves/CU with only 2 WG slots/CU. X passes its partial
// (o,l) to Y through LDS (lane-major SoA, conflict-free) with one
// __syncthreads. All X-waves (and Y-waves) in a block stream identical K/V
// addresses (L1 amplification); blockIdx&7==g keeps (b,g) pinned per XCD.
__device__ __forceinline__ void attn_zero(f32x4 o_acc[2][4], f32x4 l_acc[2]) {
#pragma unroll
    for (int mt = 0; mt < 2; ++mt) {
        l_acc[mt] = (f32x4){0.f, 0.f, 0.f, 0.f};
#pragma unroll
        for (int j = 0; j < 4; ++j) o_acc[mt][j] = (f32x4){0.f, 0.f, 0.f, 0.f};
    }
}

__device__ __forceinline__ void attn_span(
    const unsigned short* __restrict__ Qb, const unsigned short* __restrict__ Kb,
    const unsigned short* __restrict__ Vb, unsigned short* sPw,
    int qt, int kt0, int kt1, int lo, int quad,
    f32x4 o_acc[2][4], f32x4 l_acc[2])
{
    const bf16_t one = (bf16_t)1.0f;
    const bf16x8 vone = {one, one, one, one, one, one, one, one};

    bf16x8 qf[2][2];
#pragma unroll
    for (int mt = 0; mt < 2; ++mt)
#pragma unroll
        for (int h2 = 0; h2 < 2; ++h2)
            qf[mt][h2] = *(const bf16x8*)&Qb[(size_t)(qt * 32 + mt * 16 + lo) * 64 + h2 * 32 + quad * 8];

    int ktmask = qt >> 1;            // the diagonal kv-tile of this q-tile
    for (int kt = kt0; kt <= kt1; ++kt) {
        // K/V fragments straight from global (16 global_load_dwordx4 per wave)
        bf16x8 kf[4][2], vf[4][2];
#pragma unroll
        for (int tt = 0; tt < 4; ++tt) {
            kf[tt][0] = *(const bf16x8*)&Kb[(size_t)(kt * 64 + tt * 16 + lo) * 64 + quad * 8];
            kf[tt][1] = *(const bf16x8*)&Kb[(size_t)(kt * 64 + tt * 16 + lo) * 64 + 32 + quad * 8];
            vf[tt][0] = *(const bf16x8*)&Vb[(size_t)(tt * 16 + lo) * 2048 + kt * 64 + quad * 8];
            vf[tt][1] = *(const bf16x8*)&Vb[(size_t)(tt * 16 + lo) * 2048 + kt * 64 + 32 + quad * 8];
        }
        bool domask = (kt == ktmask);

#pragma unroll
        for (int mt = 0; mt < 2; ++mt) {
            // S tile: 16 q-rows x 64 kv
            f32x4 sc[4];
            __builtin_amdgcn_s_setprio(1);
#pragma unroll
            for (int ct = 0; ct < 4; ++ct) {
                f32x4 z = (f32x4){0.f, 0.f, 0.f, 0.f};
                z = MFMA16(qf[mt][0], kf[ct][0], z);
                z = MFMA16(qf[mt][1], kf[ct][1], z);
                sc[ct] = z;
            }
            __builtin_amdgcn_s_setprio(0);
            if (domask) {            // diagonal region: causal mask (absolute indices)
                int qrow0 = qt * 32 + mt * 16 + quad * 4;
#pragma unroll
                for (int ct = 0; ct < 4; ++ct)
#pragma unroll
                    for (int r = 0; r < 4; ++r)
                        if (kt * 64 + ct * 16 + lo > qrow0 + r) sc[ct][r] = -INFINITY;
            }
            // bare exp2 (scores bounded); masked -> 2^-inf = 0
#pragma unroll
            for (int ct = 0; ct < 4; ++ct)
#pragma unroll
                for (int r = 0; r < 4; ++r)
                    sc[ct][r] = __builtin_amdgcn_exp2f(sc[ct][r]);

            // P: C-layout -> LDS (wave-private, stride 68: conflict-free)
#pragma unroll
            for (int ct = 0; ct < 4; ++ct)
#pragma unroll
                for (int r = 0; r < 4; ++r)
                    sPw[(quad * 4 + r) * 68 + ct * 16 + lo] = to_bf(sc[ct][r]);

            bf16x8 pf0 = *(const bf16x8*)&sPw[lo * 68 + quad * 8];
            bf16x8 pf1 = *(const bf16x8*)&sPw[lo * 68 + 32 + quad * 8];

            __builtin_amdgcn_s_setprio(1);
            // row-sum l via ones-MFMA (every output column = rowsum, C-layout)
            l_acc[mt] = MFMA16(pf0, vone, l_acc[mt]);
            l_acc[mt] = MFMA16(pf1, vone, l_acc[mt]);

#pragma unroll
            for (int nt = 0; nt < 4; ++nt) {
                f32x4 oo = o_acc[mt][nt];
                oo = MFMA16(pf0, vf[nt][0], oo);
                oo = MFMA16(pf1, vf[nt][1], oo);
                o_acc[mt][nt] = oo;
            }
            __builtin_amdgcn_s_setprio(0);
        }
    }
}

__device__ __forceinline__ void attn_write(unsigned short* __restrict__ ctx,
    f32x4 o_acc[2][4], f32x4 l_acc[2], int b, int h, int qt, int lo, int quad)
{
#pragma unroll
    for (int mt = 0; mt < 2; ++mt)
#pragma unroll
        for (int r = 0; r < 4; ++r) {
            float inv = 1.0f / l_acc[mt][r];
            int row = qt * 32 + mt * 16 + quad * 4 + r;
#pragma unroll
            for (int nt = 0; nt < 4; ++nt) {
                size_t oi = ((size_t)(b * 2048 + row)) * 2048 + h * 64 + nt * 16 + lo;
                ctx[oi] = to_bf(o_acc[mt][nt][r] * inv);
            }
        }
}

__global__ __launch_bounds__(512) void attn_kernel(
    const unsigned short* __restrict__ q_attn,   // (b,h,s,d) bf16, pre-scaled (log2 domain)
    const unsigned short* __restrict__ k_attn,   // (b,g,s,d) bf16 post-rope
    const unsigned short* __restrict__ vt,       // (b,g,d,s) bf16
    unsigned short* __restrict__ ctx)            // (b,s,h*d) bf16
{
    __shared__ __align__(16) unsigned short sP[8][16 * 68];   // 17408 B
    __shared__ float cmb[4][40][64];                          // 40960 B, lane-major SoA

    int w = threadIdx.x >> 6;        // wave in block, 0..7
    int lane = threadIdx.x & 63;

    int g = blockIdx.x & 7;          // XCD swizzle: (b,g) working set pinned per XCD
    int rest = blockIdx.x >> 3;      // 0..63
    int b = rest >> 5;               // 0..1
    int p = rest & 31;               // pair index 0..31
    int hl = w & 3;                  // head-in-group
    int role = w >> 2;               // 0 = X (big-tile head), 1 = Y (small tile + big-tile tail)
    int h = g * 4 + hl;

    int lo = lane & 15, quad = lane >> 4;
    unsigned short* sPw = sP[w];

    const unsigned short* Qb = q_attn + (size_t)(b * 32 + h) * 2048 * 64;
    const unsigned short* Kb = k_attn + (size_t)(b * 8 + g) * 2048 * 64;
    const unsigned short* Vb = vt + (size_t)(b * 8 + g) * 64 * 2048;

    int tB = 63 - p;                 // big tile, ktmax = tB>>1 in [16,31]
    int ktmaxB = tB >> 1;

    f32x4 o_acc[2][4];
    f32x4 l_acc[2];

    if (role == 0) {
        // X: big tile, kv head [0,15] (16 iterations; never touches the diagonal)
        attn_zero(o_acc, l_acc);
        attn_span(Qb, Kb, Vb, sPw, tB, 0, 15, lo, quad, o_acc, l_acc);
        // hand partials to Y via LDS (lane-major: conflict-free)
#pragma unroll
        for (int mt = 0; mt < 2; ++mt) {
#pragma unroll
            for (int nt = 0; nt < 4; ++nt)
#pragma unroll
                for (int r = 0; r < 4; ++r)
                    cmb[hl][mt * 16 + nt * 4 + r][lane] = o_acc[mt][nt][r];
#pragma unroll
            for (int r = 0; r < 4; ++r)
                cmb[hl][32 + mt * 4 + r][lane] = l_acc[mt][r];
        }
        __syncthreads();
    } else {
        // Y: small tile p fully (1..16 iterations, owns its output)
        attn_zero(o_acc, l_acc);
        attn_span(Qb, Kb, Vb, sPw, p, 0, p >> 1, lo, quad, o_acc, l_acc);
        attn_write(ctx, o_acc, l_acc, b, h, p, lo, quad);
        // big-tile tail kt in [16, ktmaxB] (1..16 iterations, includes diagonal)
        attn_zero(o_acc, l_acc);
        attn_span(Qb, Kb, Vb, sPw, tB, 16, ktmaxB, lo, quad, o_acc, l_acc);
        __syncthreads();
        // combine with X's partial and write big tile
#pragma unroll
        for (int mt = 0; mt < 2; ++mt) {
#pragma unroll
            for (int nt = 0; nt < 4; ++nt)
#pragma unroll
                for (int r = 0; r < 4; ++r)
                    o_acc[mt][nt][r] += cmb[hl][mt * 16 + nt * 4 + r][lane];
#pragma unroll
            for (int r = 0; r < 4; ++r)
                l_acc[mt][r] += cmb[hl][32 + mt * 4 + r][lane];
        }
        attn_write(ctx, o_acc, l_acc, b, h, tB, lo, quad);
    }
}

// ---------------- launch ----------------
extern "C" void kernel_launch(void* const* d_in, const int* in_sizes, int n_in,
                              void* d_out, int out_size, void* d_ws, size_t ws_size,
                              hipStream_t stream)
{
    (void)in_sizes; (void)n_in; (void)out_size; (void)ws_size;
    const float* x       = (const float*)d_in[0];
    // d_in[1] = mask: ignored (causal mask recomputed analytically)
    const float* cosb    = (const float*)d_in[2];
    const float* sinb    = (const float*)d_in[3];
    const float* Wq      = (const float*)d_in[4];
    const float* Wk      = (const float*)d_in[5];
    const float* Wv      = (const float*)d_in[6];
    const float* Wo      = (const float*)d_in[7];
    const float* q_scale = (const float*)d_in[8];
    const float* k_scale = (const float*)d_in[9];

    float* out   = (float*)d_out;                 // (2,2048,2048)
    float* k_out = out + 8388608;                 // (2,8,2048,64)
    float* v_out = k_out + 2097152;               // (2,8,2048,64)

    char* ws = (char*)d_ws;
    size_t off = 0;
    auto alloc = [&](size_t bytes) {
        char* p = ws + off; off += (bytes + 255) & ~(size_t)255; return p;
    };
    unsigned short* x_bf   = (unsigned short*)alloc(4096ull * 2048 * 2);   // 16 MB
    unsigned short* Wqkvt  = (unsigned short*)alloc(3072ull * 2048 * 2);   // 12 MB
    unsigned short* Wot    = (unsigned short*)alloc(2048ull * 2048 * 2);   //  8 MB
    unsigned short* qkv    = (unsigned short*)alloc(4096ull * 3072 * 2);   // 24 MB
    unsigned short* q_attn = (unsigned short*)alloc(4096ull * 2048 * 2);   // 16 MB
    unsigned short* k_attn = (unsigned short*)alloc(2048ull * 2048 * 2);   //  4 MB
    unsigned short* vt     = (unsigned short*)alloc(2097152ull * 2);       //  4 MB
    unsigned short* ctx    = (unsigned short*)alloc(4096ull * 2048 * 2);   // 16 MB

    cast_x_kernel<<<8192, 256, 0, stream>>>(x, x_bf, 8388608);
    castT_kernel<<<1024, 256, 0, stream>>>(Wq, Wqkvt, 2048);
    castT_kernel<<<256, 256, 0, stream>>>(Wk, Wqkvt + 2048ull * 2048, 512);
    castT_kernel<<<256, 256, 0, stream>>>(Wv, Wqkvt + 2560ull * 2048, 512);
    castT_kernel<<<1024, 256, 0, stream>>>(Wo, Wot, 2048);

    // qkv = x @ [Wq|Wk|Wv]  (bf16 out)
    gemm_bt<<<dim3(24, 32), 256, 0, stream>>>(x_bf, Wqkvt, nullptr, qkv, 4096, 3072, 2048);

    rmsrope_kernel<<<49152, 256, 0, stream>>>(qkv, cosb, sinb, q_scale, k_scale,
                                              q_attn, k_attn, k_out, v_out);
    vtrans_kernel<<<512, 256, 0, stream>>>(qkv, vt);

    attn_kernel<<<512, 512, 0, stream>>>(q_attn, k_attn, vt, ctx);

    // out = ctx @ Wo  (fp32 out)
    gemm_bt<<<dim3(16, 32), 256, 0, stream>>>(ctx, Wot, out, nullptr, 4096, 2048, 2048);
}

// Round 4
// 453.144 us; speedup vs baseline: 1.0158x; 1.0158x over previous
//
#include <hip/hip_runtime.h>

typedef __bf16 bf16_t;
typedef bf16_t bf16x8 __attribute__((ext_vector_type(8)));
typedef float f32x4 __attribute__((ext_vector_type(4)));

#define MFMA16(a, b, c) __builtin_amdgcn_mfma_f32_16x16x32_bf16(a, b, c, 0, 0, 0)

__device__ __forceinline__ unsigned short f2bf(float f) {
    union { float f; unsigned u; } v; v.f = f;
    unsigned r = v.u + 0x7FFFu + ((v.u >> 16) & 1u);  // RNE
    return (unsigned short)(r >> 16);
}
__device__ __forceinline__ float bf2f(unsigned short h) {
    union { unsigned u; float f; } v; v.u = ((unsigned)h) << 16;
    return v.f;
}
__device__ __forceinline__ unsigned short to_bf(float f) {
    bf16_t b = (bf16_t)f;                 // gfx950 native v_cvt (RNE)
    return __builtin_bit_cast(unsigned short, b);
}

// async global->LDS, 16B per lane; LDS dst is wave-uniform base + lane*16
__device__ __forceinline__ void gll16(const unsigned short* g, unsigned short* l) {
    __builtin_amdgcn_global_load_lds(
        (const __attribute__((address_space(1))) unsigned int*)g,
        (__attribute__((address_space(3))) unsigned int*)l, 16, 0, 0);
}

// ---------------- cast kernels ----------------
__global__ __launch_bounds__(256) void cast_x_kernel(const float* __restrict__ src,
                                                     unsigned short* __restrict__ dst, int n) {
    int i = (blockIdx.x * 256 + threadIdx.x) * 4;
    if (i >= n) return;
    float4 v = *(const float4*)&src[i];
    union { unsigned short e[4]; uint2 u; } p;
    p.e[0] = f2bf(v.x); p.e[1] = f2bf(v.y); p.e[2] = f2bf(v.z); p.e[3] = f2bf(v.w);
    *(uint2*)&dst[i] = p.u;
}

// src is K x N row-major fp32 (K=2048); dst is N x K row-major bf16 (B^T).
// LDS-tiled 64x64 transpose: coalesced reads AND writes.
__global__ __launch_bounds__(256) void castT_kernel(const float* __restrict__ src,
                                                    unsigned short* __restrict__ dst,
                                                    int N) {
    __shared__ __align__(16) unsigned short sT[64 * 68];
    int nt = blockIdx.x >> 5;            // K/64 == 32 (K fixed at 2048)
    int kt = blockIdx.x & 31;
    int k0 = kt * 64, n0 = nt * 64;
    int t = threadIdx.x;
#pragma unroll
    for (int c = t; c < 1024; c += 256) {
        int r = c >> 4, c4 = c & 15;
        float4 v = *(const float4*)&src[(size_t)(k0 + r) * N + n0 + c4 * 4];
        union { unsigned short e[4]; uint2 u; } p;
        p.e[0] = f2bf(v.x); p.e[1] = f2bf(v.y); p.e[2] = f2bf(v.z); p.e[3] = f2bf(v.w);
        *(uint2*)&sT[r * 68 + c4 * 4] = p.u;   // sT[k-row][n-col]
    }
    __syncthreads();
#pragma unroll
    for (int c = t; c < 512; c += 256) {
        int n = c >> 3, cb = c & 7;
        union { unsigned short e[8]; uint4 v; } u;
#pragma unroll
        for (int j = 0; j < 8; ++j) u.e[j] = sT[(cb * 8 + j) * 68 + n];
        *(uint4*)&dst[(size_t)(n0 + n) * 2048 + k0 + cb * 8] = u.v;
    }
}

// ---------------- GEMM: C(MxN) = A(MxK,bf16) * Bt(NxK,bf16)^T ----------------
// m97 structure: global_load_lds width=16 staging, unpadded stride-64 LDS.
__global__ __launch_bounds__(256) void gemm_bt(
    const unsigned short* __restrict__ A,
    const unsigned short* __restrict__ Bt,
    float* __restrict__ Cf, unsigned short* __restrict__ Cb,
    int M, int N, int K)
{
    __shared__ __align__(16) unsigned short sA[128 * 64];
    __shared__ __align__(16) unsigned short sB[128 * 64];
    int n0 = blockIdx.x * 128, m0 = blockIdx.y * 128;
    int tid = threadIdx.x;
    int lane = tid & 63, w = tid >> 6;
    int wm = (w >> 1) * 64, wn = (w & 1) * 64;
    int lo = lane & 15, quad = lane >> 4;

    // wave w stages rows [w*32, w*32+32): 4 chunks of 8 rows x 64 cols (1024 B)
    int srow = w * 32 + (lane >> 3);
    int scol = (lane & 7) * 8;
    const unsigned short* Ag = &A[(size_t)(m0 + srow) * K + scol];
    const unsigned short* Bg = &Bt[(size_t)(n0 + srow) * K + scol];

    f32x4 acc[4][4];
#pragma unroll
    for (int i = 0; i < 4; ++i)
#pragma unroll
        for (int j = 0; j < 4; ++j) acc[i][j] = (f32x4){0.f, 0.f, 0.f, 0.f};

    for (int kt = 0; kt < K; kt += 64) {
#pragma unroll
        for (int c = 0; c < 4; ++c) {
            gll16(Ag + (size_t)(c * 8) * K + kt, &sA[(w * 4 + c) * 512]);
            gll16(Bg + (size_t)(c * 8) * K + kt, &sB[(w * 4 + c) * 512]);
        }
        __syncthreads();
#pragma unroll
        for (int ks = 0; ks < 64; ks += 32) {
            bf16x8 af[4], bfr[4];
#pragma unroll
            for (int mi = 0; mi < 4; ++mi)
                af[mi] = *(const bf16x8*)&sA[(wm + mi * 16 + lo) * 64 + ks + quad * 8];
#pragma unroll
            for (int ni = 0; ni < 4; ++ni)
                bfr[ni] = *(const bf16x8*)&sB[(wn + ni * 16 + lo) * 64 + ks + quad * 8];
#pragma unroll
            for (int mi = 0; mi < 4; ++mi)
#pragma unroll
                for (int ni = 0; ni < 4; ++ni)
                    acc[mi][ni] = MFMA16(af[mi], bfr[ni], acc[mi][ni]);
        }
        __syncthreads();
    }

#pragma unroll
    for (int mi = 0; mi < 4; ++mi)
#pragma unroll
        for (int ni = 0; ni < 4; ++ni)
#pragma unroll
            for (int r = 0; r < 4; ++r) {
                int row = m0 + wm + mi * 16 + quad * 4 + r;
                int col = n0 + wn + ni * 16 + lo;
                if (Cf) Cf[(size_t)row * N + col] = acc[mi][ni][r];
                else    Cb[(size_t)row * N + col] = f2bf(acc[mi][ni][r]);
            }
}

// ---------------- RMSNorm + RoPE (+ scatter to outputs) ----------------
// qkv: (B*S, 3072) bf16 rows = [q 2048 | k 512 | v 512]
__global__ __launch_bounds__(256) void rmsrope_kernel(
    const unsigned short* __restrict__ qkv,
    const float* __restrict__ cosb, const float* __restrict__ sinb,
    const float* __restrict__ q_scale, const float* __restrict__ k_scale,
    unsigned short* __restrict__ q_attn, unsigned short* __restrict__ k_attn,
    float* __restrict__ k_out, float* __restrict__ v_out)
{
    int wid = blockIdx.x * 4 + (threadIdx.x >> 6);   // one wave per 64-elem row
    int lane = threadIdx.x & 63;
    int t = wid % 48;          // 0..31 q-head, 32..39 k-group, 40..47 v-group
    int bs = wid / 48;         // 0..4095
    int b = bs >> 11, s = bs & 2047;

    if (t >= 40) {             // v: straight copy to output (b,g,s,d) fp32
        int g = t - 40;
        float val = bf2f(qkv[(size_t)bs * 3072 + 2560 + g * 64 + lane]);
        v_out[(size_t)((b * 8 + g) * 2048 + s) * 64 + lane] = val;
        return;
    }
    bool is_q = (t < 32);
    int col = is_q ? (t * 64) : (2048 + (t - 32) * 64);
    float val = bf2f(qkv[(size_t)bs * 3072 + col + lane]);
    float ss = val * val;
#pragma unroll
    for (int m = 1; m < 64; m <<= 1) ss += __shfl_xor(ss, m);
    float rs = rsqrtf(ss * (1.0f / 64.0f) + 1e-6f);
    float scl = is_q ? q_scale[lane] : k_scale[lane];
    float xn = val * rs * scl;
    float other = __shfl_xor(xn, 32);
    float rot = (lane < 32) ? -other : other;     // [-x2, x1]
    float o = xn * cosb[s * 64 + lane] + rot * sinb[s * 64 + lane];
    if (is_q) {
        // fold 1/sqrt(D)=0.125 and log2(e) into q (attention works in exp2 domain)
        q_attn[(size_t)((b * 32 + t) * 2048 + s) * 64 + lane] = to_bf(o * (0.125f * 1.44269504f));
    } else {
        int g = t - 32;
        size_t idx = (size_t)((b * 8 + g) * 2048 + s) * 64 + lane;
        k_attn[idx] = to_bf(o);
        k_out[idx] = o;
    }
}

// ---------------- V transpose: qkv v-cols -> vt (b,g,d,s) bf16 ----------------
__global__ __launch_bounds__(256) void vtrans_kernel(
    const unsigned short* __restrict__ qkv, unsigned short* __restrict__ vt)
{
    __shared__ __align__(16) unsigned short sT[64 * 68];
    int idx = blockIdx.x;            // B*G*32 = 512
    int st = idx & 31, g = (idx >> 5) & 7, b = idx >> 8;
    int tid = threadIdx.x;
#pragma unroll
    for (int c = tid; c < 512; c += 256) {
        int r = c >> 3, cb = c & 7;
        *(uint4*)&sT[r * 68 + cb * 8] =
            *(const uint4*)&qkv[(size_t)(b * 2048 + st * 64 + r) * 3072 + 2560 + g * 64 + cb * 8];
    }
    __syncthreads();
#pragma unroll
    for (int c = tid; c < 512; c += 256) {
        int d = c >> 3, cb = c & 7;
        union { unsigned short e[8]; uint4 v; } u;
#pragma unroll
        for (int j = 0; j < 8; ++j) u.e[j] = sT[(cb * 8 + j) * 68 + d];
        *(uint4*)&vt[((size_t)(b * 8 + g) * 64 + d) * 2048 + st * 64 + cb * 8] = u.v;
    }
}

// ---------------- flash attention, causal, GQA ----------------
// R3 post-mortem: occupancy is pinned at ~8 waves/CU no matter the grid shape
// (1-wave x2048, 4-wave x512, 8-wave split-KV all = 134-138us, MfmaUtil 11.5%).
// Per-CU arithmetic: ~1220 cy/wave-iteration vs ~250 cy of pipe work — the gap
// is the iteration-leading 16 L2-latency loads feeding QK immediately; with 2
// waves/SIMD both waves hit the same vmcnt wall. THIS version removes that
// stall from the serial chain via register software-pipelining:
//   - K(kt+1) prefetched into a ping-pong buffer during COMPUTE(kt)
//     (K is consumed first, at QK — the critical load)
//   - V(kt) issued at the top of iteration kt; its ~500cy latency hides under
//     QK + exp2 + P LDS round-trip before PV consumes it
// Only K is double-buffered (+32 VGPR). Buffers ping-pong with static names
// (no runtime indexing -> no scratch). Shell: 4 independent waves per block
// sharing (b,g,p) => identical K/V addresses (L1 amplification), blockIdx&7==g
// pins the working set per XCD. Wave task = pair (p, 63-p): uniform 33 iters.
__global__ __launch_bounds__(256) void attn_kernel(
    const unsigned short* __restrict__ q_attn,   // (b,h,s,d) bf16, pre-scaled (log2 domain)
    const unsigned short* __restrict__ k_attn,   // (b,g,s,d) bf16 post-rope
    const unsigned short* __restrict__ vt,       // (b,g,d,s) bf16
    unsigned short* __restrict__ ctx)            // (b,s,h*d) bf16
{
    __shared__ __align__(16) unsigned short sP[4][16 * 68];

    int w = threadIdx.x >> 6;        // wave in block, 0..3
    int lane = threadIdx.x & 63;

    int g = blockIdx.x & 7;          // XCD swizzle: (b,g) working set pinned per XCD
    int rest = blockIdx.x >> 3;      // 0..63
    int u = rest * 4 + w;            // 0..255 task id within this g
    int b = u >> 7;                  // 0..1
    int s2 = u & 127;
    int hl = s2 & 3, p = s2 >> 2;    // head-in-group (==w), pair index 0..31
    int h = g * 4 + hl;

    int lo = lane & 15, quad = lane >> 4;
    unsigned short* sPw = sP[w];

    const unsigned short* Qb = q_attn + (size_t)(b * 32 + h) * 2048 * 64;
    const unsigned short* Kb = k_attn + (size_t)(b * 8 + g) * 2048 * 64;
    const unsigned short* Vb = vt + (size_t)(b * 8 + g) * 64 * 2048;

    const bf16_t one = (bf16_t)1.0f;
    const bf16x8 vone = {one, one, one, one, one, one, one, one};

#pragma unroll
    for (int t2 = 0; t2 < 2; ++t2) {
        int qt = t2 ? (63 - p) : p;
        int ktmax = qt >> 1;             // kv tiles 0..ktmax (tile = 64 kv)

        bf16x8 qf[2][2];
#pragma unroll
        for (int mt = 0; mt < 2; ++mt)
#pragma unroll
            for (int h2 = 0; h2 < 2; ++h2)
                qf[mt][h2] = *(const bf16x8*)&Qb[(size_t)(qt * 32 + mt * 16 + lo) * 64 + h2 * 32 + quad * 8];

        f32x4 o_acc[2][4];
        f32x4 l_acc[2];
#pragma unroll
        for (int mt = 0; mt < 2; ++mt) {
            l_acc[mt] = (f32x4){0.f, 0.f, 0.f, 0.f};
#pragma unroll
            for (int j = 0; j < 4; ++j) o_acc[mt][j] = (f32x4){0.f, 0.f, 0.f, 0.f};
        }

        auto LOADK = [&](bf16x8 (&kf)[4][2], int kt) {
#pragma unroll
            for (int tt = 0; tt < 4; ++tt) {
                kf[tt][0] = *(const bf16x8*)&Kb[(size_t)(kt * 64 + tt * 16 + lo) * 64 + quad * 8];
                kf[tt][1] = *(const bf16x8*)&Kb[(size_t)(kt * 64 + tt * 16 + lo) * 64 + 32 + quad * 8];
            }
        };
        auto LOADV = [&](bf16x8 (&vf)[4][2], int kt) {
#pragma unroll
            for (int tt = 0; tt < 4; ++tt) {
                vf[tt][0] = *(const bf16x8*)&Vb[(size_t)(tt * 16 + lo) * 2048 + kt * 64 + quad * 8];
                vf[tt][1] = *(const bf16x8*)&Vb[(size_t)(tt * 16 + lo) * 2048 + kt * 64 + 32 + quad * 8];
            }
        };
        auto COMPUTE = [&](bf16x8 (&kf)[4][2], bf16x8 (&vf)[4][2], int kt) {
            bool domask = (kt == ktmax);
#pragma unroll
            for (int mt = 0; mt < 2; ++mt) {
                // S tile: 16 q-rows x 64 kv
                f32x4 sc[4];
                __builtin_amdgcn_s_setprio(1);
#pragma unroll
                for (int ct = 0; ct < 4; ++ct) {
                    f32x4 z = (f32x4){0.f, 0.f, 0.f, 0.f};
                    z = MFMA16(qf[mt][0], kf[ct][0], z);
                    z = MFMA16(qf[mt][1], kf[ct][1], z);
                    sc[ct] = z;
                }
                __builtin_amdgcn_s_setprio(0);
                if (domask) {        // diagonal region: causal mask (absolute indices)
                    int qrow0 = qt * 32 + mt * 16 + quad * 4;
#pragma unroll
                    for (int ct = 0; ct < 4; ++ct)
#pragma unroll
                        for (int r = 0; r < 4; ++r)
                            if (kt * 64 + ct * 16 + lo > qrow0 + r) sc[ct][r] = -INFINITY;
                }
                // bare exp2 (scores bounded); masked -> 2^-inf = 0
#pragma unroll
                for (int ct = 0; ct < 4; ++ct)
#pragma unroll
                    for (int r = 0; r < 4; ++r)
                        sc[ct][r] = __builtin_amdgcn_exp2f(sc[ct][r]);

                // P: C-layout -> LDS (wave-private, stride 68: conflict-free)
#pragma unroll
                for (int ct = 0; ct < 4; ++ct)
#pragma unroll
                    for (int r = 0; r < 4; ++r)
                        sPw[(quad * 4 + r) * 68 + ct * 16 + lo] = to_bf(sc[ct][r]);

                bf16x8 pf0 = *(const bf16x8*)&sPw[lo * 68 + quad * 8];
                bf16x8 pf1 = *(const bf16x8*)&sPw[lo * 68 + 32 + quad * 8];

                __builtin_amdgcn_s_setprio(1);
                // row-sum l via ones-MFMA (every output column = rowsum, C-layout)
                l_acc[mt] = MFMA16(pf0, vone, l_acc[mt]);
                l_acc[mt] = MFMA16(pf1, vone, l_acc[mt]);

#pragma unroll
                for (int nt = 0; nt < 4; ++nt) {
                    f32x4 oo = o_acc[mt][nt];
                    oo = MFMA16(pf0, vf[nt][0], oo);
                    oo = MFMA16(pf1, vf[nt][1], oo);
                    o_acc[mt][nt] = oo;
                }
                __builtin_amdgcn_s_setprio(0);
            }
        };

        // --- software-pipelined kt loop: K double-buffered, V issued early ---
        bf16x8 kA[4][2], kB[4][2], vf[4][2];
        LOADK(kA, 0);
        int kt = 0;
        while (true) {
            LOADV(vf, kt);                       // V(kt): covered by QK+softmax
            if (kt < ktmax) LOADK(kB, kt + 1);   // prefetch next K
            COMPUTE(kA, vf, kt);
            ++kt;
            if (kt > ktmax) break;
            LOADV(vf, kt);
            if (kt < ktmax) LOADK(kA, kt + 1);
            COMPUTE(kB, vf, kt);
            ++kt;
            if (kt > ktmax) break;
        }

#pragma unroll
        for (int mt = 0; mt < 2; ++mt)
#pragma unroll
            for (int r = 0; r < 4; ++r) {
                float inv = 1.0f / l_acc[mt][r];
                int row = qt * 32 + mt * 16 + quad * 4 + r;
#pragma unroll
                for (int nt = 0; nt < 4; ++nt) {
                    size_t oi = ((size_t)(b * 2048 + row)) * 2048 + h * 64 + nt * 16 + lo;
                    ctx[oi] = to_bf(o_acc[mt][nt][r] * inv);
                }
            }
    }
}

// ---------------- launch ----------------
extern "C" void kernel_launch(void* const* d_in, const int* in_sizes, int n_in,
                              void* d_out, int out_size, void* d_ws, size_t ws_size,
                              hipStream_t stream)
{
    (void)in_sizes; (void)n_in; (void)out_size; (void)ws_size;
    const float* x       = (const float*)d_in[0];
    // d_in[1] = mask: ignored (causal mask recomputed analytically)
    const float* cosb    = (const float*)d_in[2];
    const float* sinb    = (const float*)d_in[3];
    const float* Wq      = (const float*)d_in[4];
    const float* Wk      = (const float*)d_in[5];
    const float* Wv      = (const float*)d_in[6];
    const float* Wo      = (const float*)d_in[7];
    const float* q_scale = (const float*)d_in[8];
    const float* k_scale = (const float*)d_in[9];

    float* out   = (float*)d_out;                 // (2,2048,2048)
    float* k_out = out + 8388608;                 // (2,8,2048,64)
    float* v_out = k_out + 2097152;               // (2,8,2048,64)

    char* ws = (char*)d_ws;
    size_t off = 0;
    auto alloc = [&](size_t bytes) {
        char* p = ws + off; off += (bytes + 255) & ~(size_t)255; return p;
    };
    unsigned short* x_bf   = (unsigned short*)alloc(4096ull * 2048 * 2);   // 16 MB
    unsigned short* Wqkvt  = (unsigned short*)alloc(3072ull * 2048 * 2);   // 12 MB
    unsigned short* Wot    = (unsigned short*)alloc(2048ull * 2048 * 2);   //  8 MB
    unsigned short* qkv    = (unsigned short*)alloc(4096ull * 3072 * 2);   // 24 MB
    unsigned short* q_attn = (unsigned short*)alloc(4096ull * 2048 * 2);   // 16 MB
    unsigned short* k_attn = (unsigned short*)alloc(2048ull * 2048 * 2);   //  4 MB
    unsigned short* vt     = (unsigned short*)alloc(2097152ull * 2);       //  4 MB
    unsigned short* ctx    = (unsigned short*)alloc(4096ull * 2048 * 2);   // 16 MB

    cast_x_kernel<<<8192, 256, 0, stream>>>(x, x_bf, 8388608);
    castT_kernel<<<1024, 256, 0, stream>>>(Wq, Wqkvt, 2048);
    castT_kernel<<<256, 256, 0, stream>>>(Wk, Wqkvt + 2048ull * 2048, 512);
    castT_kernel<<<256, 256, 0, stream>>>(Wv, Wqkvt + 2560ull * 2048, 512);
    castT_kernel<<<1024, 256, 0, stream>>>(Wo, Wot, 2048);

    // qkv = x @ [Wq|Wk|Wv]  (bf16 out)
    gemm_bt<<<dim3(24, 32), 256, 0, stream>>>(x_bf, Wqkvt, nullptr, qkv, 4096, 3072, 2048);

    rmsrope_kernel<<<49152, 256, 0, stream>>>(qkv, cosb, sinb, q_scale, k_scale,
                                              q_attn, k_attn, k_out, v_out);
    vtrans_kernel<<<512, 256, 0, stream>>>(qkv, vt);

    attn_kernel<<<512, 256, 0, stream>>>(q_attn, k_attn, vt, ctx);

    // out = ctx @ Wo  (fp32 out)
    gemm_bt<<<dim3(16, 32), 256, 0, stream>>>(ctx, Wot, out, nullptr, 4096, 2048, 2048);
}

// Round 5
// 435.903 us; speedup vs baseline: 1.0560x; 1.0396x over previous
//
#include <hip/hip_runtime.h>

typedef __bf16 bf16_t;
typedef bf16_t bf16x8 __attribute__((ext_vector_type(8)));
typedef float f32x4 __attribute__((ext_vector_type(4)));

#define MFMA16(a, b, c) __builtin_amdgcn_mfma_f32_16x16x32_bf16(a, b, c, 0, 0, 0)

__device__ __forceinline__ unsigned short f2bf(float f) {
    union { float f; unsigned u; } v; v.f = f;
    unsigned r = v.u + 0x7FFFu + ((v.u >> 16) & 1u);  // RNE
    return (unsigned short)(r >> 16);
}
__device__ __forceinline__ float bf2f(unsigned short h) {
    union { unsigned u; float f; } v; v.u = ((unsigned)h) << 16;
    return v.f;
}
__device__ __forceinline__ unsigned short to_bf(float f) {
    bf16_t b = (bf16_t)f;                 // gfx950 native v_cvt (RNE)
    return __builtin_bit_cast(unsigned short, b);
}

// async global->LDS, 16B per lane; LDS dst is wave-uniform base + lane*16,
// global src address is per-lane.
__device__ __forceinline__ void gll16(const unsigned short* g, unsigned short* l) {
    __builtin_amdgcn_global_load_lds(
        (const __attribute__((address_space(1))) unsigned int*)g,
        (__attribute__((address_space(3))) unsigned int*)l, 16, 0, 0);
}

// ---------------- cast kernels ----------------
__global__ __launch_bounds__(256) void cast_x_kernel(const float* __restrict__ src,
                                                     unsigned short* __restrict__ dst, int n) {
    int i = (blockIdx.x * 256 + threadIdx.x) * 4;
    if (i >= n) return;
    float4 v = *(const float4*)&src[i];
    union { unsigned short e[4]; uint2 u; } p;
    p.e[0] = f2bf(v.x); p.e[1] = f2bf(v.y); p.e[2] = f2bf(v.z); p.e[3] = f2bf(v.w);
    *(uint2*)&dst[i] = p.u;
}

// src is K x N row-major fp32 (K=2048); dst is N x K row-major bf16 (B^T).
// LDS-tiled 64x64 transpose: coalesced reads AND writes.
__global__ __launch_bounds__(256) void castT_kernel(const float* __restrict__ src,
                                                    unsigned short* __restrict__ dst,
                                                    int N) {
    __shared__ __align__(16) unsigned short sT[64 * 68];
    int nt = blockIdx.x >> 5;            // K/64 == 32 (K fixed at 2048)
    int kt = blockIdx.x & 31;
    int k0 = kt * 64, n0 = nt * 64;
    int t = threadIdx.x;
#pragma unroll
    for (int c = t; c < 1024; c += 256) {
        int r = c >> 4, c4 = c & 15;
        float4 v = *(const float4*)&src[(size_t)(k0 + r) * N + n0 + c4 * 4];
        union { unsigned short e[4]; uint2 u; } p;
        p.e[0] = f2bf(v.x); p.e[1] = f2bf(v.y); p.e[2] = f2bf(v.z); p.e[3] = f2bf(v.w);
        *(uint2*)&sT[r * 68 + c4 * 4] = p.u;   // sT[k-row][n-col]
    }
    __syncthreads();
#pragma unroll
    for (int c = t; c < 512; c += 256) {
        int n = c >> 3, cb = c & 7;
        union { unsigned short e[8]; uint4 v; } u;
#pragma unroll
        for (int j = 0; j < 8; ++j) u.e[j] = sT[(cb * 8 + j) * 68 + n];
        *(uint4*)&dst[(size_t)(n0 + n) * 2048 + k0 + cb * 8] = u.v;
    }
}

// ---------------- GEMM: C(MxN) = A(MxK,bf16) * Bt(NxK,bf16)^T ----------------
// m97 structure: global_load_lds width=16 staging, unpadded stride-64 LDS.
__global__ __launch_bounds__(256) void gemm_bt(
    const unsigned short* __restrict__ A,
    const unsigned short* __restrict__ Bt,
    float* __restrict__ Cf, unsigned short* __restrict__ Cb,
    int M, int N, int K)
{
    __shared__ __align__(16) unsigned short sA[128 * 64];
    __shared__ __align__(16) unsigned short sB[128 * 64];
    int n0 = blockIdx.x * 128, m0 = blockIdx.y * 128;
    int tid = threadIdx.x;
    int lane = tid & 63, w = tid >> 6;
    int wm = (w >> 1) * 64, wn = (w & 1) * 64;
    int lo = lane & 15, quad = lane >> 4;

    // wave w stages rows [w*32, w*32+32): 4 chunks of 8 rows x 64 cols (1024 B)
    int srow = w * 32 + (lane >> 3);
    int scol = (lane & 7) * 8;
    const unsigned short* Ag = &A[(size_t)(m0 + srow) * K + scol];
    const unsigned short* Bg = &Bt[(size_t)(n0 + srow) * K + scol];

    f32x4 acc[4][4];
#pragma unroll
    for (int i = 0; i < 4; ++i)
#pragma unroll
        for (int j = 0; j < 4; ++j) acc[i][j] = (f32x4){0.f, 0.f, 0.f, 0.f};

    for (int kt = 0; kt < K; kt += 64) {
#pragma unroll
        for (int c = 0; c < 4; ++c) {
            gll16(Ag + (size_t)(c * 8) * K + kt, &sA[(w * 4 + c) * 512]);
            gll16(Bg + (size_t)(c * 8) * K + kt, &sB[(w * 4 + c) * 512]);
        }
        __syncthreads();
#pragma unroll
        for (int ks = 0; ks < 64; ks += 32) {
            bf16x8 af[4], bfr[4];
#pragma unroll
            for (int mi = 0; mi < 4; ++mi)
                af[mi] = *(const bf16x8*)&sA[(wm + mi * 16 + lo) * 64 + ks + quad * 8];
#pragma unroll
            for (int ni = 0; ni < 4; ++ni)
                bfr[ni] = *(const bf16x8*)&sB[(wn + ni * 16 + lo) * 64 + ks + quad * 8];
#pragma unroll
            for (int mi = 0; mi < 4; ++mi)
#pragma unroll
                for (int ni = 0; ni < 4; ++ni)
                    acc[mi][ni] = MFMA16(af[mi], bfr[ni], acc[mi][ni]);
        }
        __syncthreads();
    }

#pragma unroll
    for (int mi = 0; mi < 4; ++mi)
#pragma unroll
        for (int ni = 0; ni < 4; ++ni)
#pragma unroll
            for (int r = 0; r < 4; ++r) {
                int row = m0 + wm + mi * 16 + quad * 4 + r;
                int col = n0 + wn + ni * 16 + lo;
                if (Cf) Cf[(size_t)row * N + col] = acc[mi][ni][r];
                else    Cb[(size_t)row * N + col] = f2bf(acc[mi][ni][r]);
            }
}

// ---------------- RMSNorm + RoPE (+ scatter to outputs) ----------------
// qkv: (B*S, 3072) bf16 rows = [q 2048 | k 512 | v 512]
__global__ __launch_bounds__(256) void rmsrope_kernel(
    const unsigned short* __restrict__ qkv,
    const float* __restrict__ cosb, const float* __restrict__ sinb,
    const float* __restrict__ q_scale, const float* __restrict__ k_scale,
    unsigned short* __restrict__ q_attn, unsigned short* __restrict__ k_attn,
    float* __restrict__ k_out, float* __restrict__ v_out)
{
    int wid = blockIdx.x * 4 + (threadIdx.x >> 6);   // one wave per 64-elem row
    int lane = threadIdx.x & 63;
    int t = wid % 48;          // 0..31 q-head, 32..39 k-group, 40..47 v-group
    int bs = wid / 48;         // 0..4095
    int b = bs >> 11, s = bs & 2047;

    if (t >= 40) {             // v: straight copy to output (b,g,s,d) fp32
        int g = t - 40;
        float val = bf2f(qkv[(size_t)bs * 3072 + 2560 + g * 64 + lane]);
        v_out[(size_t)((b * 8 + g) * 2048 + s) * 64 + lane] = val;
        return;
    }
    bool is_q = (t < 32);
    int col = is_q ? (t * 64) : (2048 + (t - 32) * 64);
    float val = bf2f(qkv[(size_t)bs * 3072 + col + lane]);
    float ss = val * val;
#pragma unroll
    for (int m = 1; m < 64; m <<= 1) ss += __shfl_xor(ss, m);
    float rs = rsqrtf(ss * (1.0f / 64.0f) + 1e-6f);
    float scl = is_q ? q_scale[lane] : k_scale[lane];
    float xn = val * rs * scl;
    float other = __shfl_xor(xn, 32);
    float rot = (lane < 32) ? -other : other;     // [-x2, x1]
    float o = xn * cosb[s * 64 + lane] + rot * sinb[s * 64 + lane];
    if (is_q) {
        // fold 1/sqrt(D)=0.125 and log2(e) into q (attention works in exp2 domain)
        q_attn[(size_t)((b * 32 + t) * 2048 + s) * 64 + lane] = to_bf(o * (0.125f * 1.44269504f));
    } else {
        int g = t - 32;
        size_t idx = (size_t)((b * 8 + g) * 2048 + s) * 64 + lane;
        k_attn[idx] = to_bf(o);
        k_out[idx] = o;
    }
}

// ---------------- V transpose: qkv v-cols -> vt (b,g,d,s) bf16 ----------------
__global__ __launch_bounds__(256) void vtrans_kernel(
    const unsigned short* __restrict__ qkv, unsigned short* __restrict__ vt)
{
    __shared__ __align__(16) unsigned short sT[64 * 68];
    int idx = blockIdx.x;            // B*G*32 = 512
    int st = idx & 31, g = (idx >> 5) & 7, b = idx >> 8;
    int tid = threadIdx.x;
#pragma unroll
    for (int c = tid; c < 512; c += 256) {
        int r = c >> 3, cb = c & 7;
        *(uint4*)&sT[r * 68 + cb * 8] =
            *(const uint4*)&qkv[(size_t)(b * 2048 + st * 64 + r) * 3072 + 2560 + g * 64 + cb * 8];
    }
    __syncthreads();
#pragma unroll
    for (int c = tid; c < 512; c += 256) {
        int d = c >> 3, cb = c & 7;
        union { unsigned short e[8]; uint4 v; } u;
#pragma unroll
        for (int j = 0; j < 8; ++j) u.e[j] = sT[(cb * 8 + j) * 68 + d];
        *(uint4*)&vt[((size_t)(b * 8 + g) * 64 + d) * 2048 + st * 64 + cb * 8] = u.v;
    }
}

// ---------------- flash attention, causal, GQA ----------------
// R4 post-mortem: residency is register-capped at ~2 waves/SIMD (acc regs sit
// on top of reported VGPR_Count; 108 arch + acc ~ 200 -> 2/SIMD; R4's 148 ->
// 1/SIMD). More waves is a dead axis. At fixed 8 waves/CU, dur was invariant
// across R0-R3 because each wave pulls 16KB/iter through the CU's VMEM return
// path: ~103 B/cy/CU — the saturated resource. THIS version stages K/V tiles
// into LDS ONCE per block (global_load_lds, double-buffered, issue-early) and
// shares them across the block's 4 waves (4 heads, same (b,g,p)): per-CU VMEM
// delivery drops 4x, and the kt chain loses the L2 latency.
//   - LDS K/V tiles are [64][64] bf16 (128B rows). Column-slice ds_read_b128
//     is bank-degenerate, so T2 XOR-swizzle byte^=(row&7)<<4, implemented per
//     rule #21: linear LDS dest + INVERSE-swizzled global source address +
//     swizzled read address.
//   - Each block sweeps kv ONCE for the pair (p, 63-p): the small tile rides
//     the big tile's staged prefix, and kf/vf fragments are read once per
//     iteration and used for both tiles' MFMAs.
//   - Blocks are non-uniform (17..32 iters): long tasks dispatched first,
//     round-2 blocks reversed so CU sums are ~uniform (49).
__global__ __launch_bounds__(256) void attn_kernel(
    const unsigned short* __restrict__ q_attn,   // (b,h,s,d) bf16, pre-scaled (log2 domain)
    const unsigned short* __restrict__ k_attn,   // (b,g,s,d) bf16 post-rope
    const unsigned short* __restrict__ vt,       // (b,g,d,s) bf16
    unsigned short* __restrict__ ctx)            // (b,s,h*d) bf16
{
    __shared__ __align__(16) unsigned short sK[2][4096];   // 16 KB (2 x 64x64 bf16)
    __shared__ __align__(16) unsigned short sV[2][4096];   // 16 KB
    __shared__ __align__(16) unsigned short sP[4][16 * 68];// 8.5 KB (wave-private)

    int w = threadIdx.x >> 6;        // wave in block = head-in-group, 0..3
    int lane = threadIdx.x & 63;

    int g = blockIdx.x & 7;          // XCD swizzle: (b,g) working set pinned per XCD
    int rest = blockIdx.x >> 3;      // 0..63
    int b = rest & 1;
    int pr = rest >> 1;              // 0..31 in dispatch order
    int p = (pr < 16) ? pr : (47 - pr);  // long tasks first; round 2 reversed
    int h = g * 4 + w;

    int lo = lane & 15, quad = lane >> 4;
    unsigned short* sPw = sP[w];

    const unsigned short* Qb = q_attn + (size_t)(b * 32 + h) * 2048 * 64;
    const unsigned short* Kb = k_attn + (size_t)(b * 8 + g) * 2048 * 64;
    const unsigned short* Vb = vt + (size_t)(b * 8 + g) * 64 * 2048;

    int qtS = p, qtB = 63 - p;
    int ktmaxS = p >> 1;             // small tile's diagonal kv-tile
    int nt = ((63 - p) >> 1) + 1;    // kv tiles for the big tile: 17..32

    // staging lane geometry: chunk = 8 rows x 64 cols (1 KB); lane l covers
    // row rsub of the chunk at inverse-swizzled column csw.
    int rsub = lane >> 3;                  // 0..7 (== row & 7 within chunk)
    int csw  = ((lane & 7) ^ rsub) << 3;   // ushort units

    auto STAGE = [&](int buf, int kt) {
#pragma unroll
        for (int i = 0; i < 2; ++i) {
            int c = w + i * 4;             // this wave's chunks: w, w+4
            gll16(Kb + (size_t)(kt * 64 + c * 8 + rsub) * 64 + csw, &sK[buf][c * 512]);
            gll16(Vb + (size_t)(c * 8 + rsub) * 2048 + kt * 64 + csw, &sV[buf][c * 512]);
        }
    };

    const bf16_t one = (bf16_t)1.0f;
    const bf16x8 vone = {one, one, one, one, one, one, one, one};

    // Q fragments for both tiles (held in registers for the whole sweep)
    bf16x8 qfS[2][2], qfB[2][2];
#pragma unroll
    for (int mt = 0; mt < 2; ++mt)
#pragma unroll
        for (int h2 = 0; h2 < 2; ++h2) {
            qfS[mt][h2] = *(const bf16x8*)&Qb[(size_t)(qtS * 32 + mt * 16 + lo) * 64 + h2 * 32 + quad * 8];
            qfB[mt][h2] = *(const bf16x8*)&Qb[(size_t)(qtB * 32 + mt * 16 + lo) * 64 + h2 * 32 + quad * 8];
        }

    f32x4 oS[2][4], oB[2][4], lS[2], lB[2];
#pragma unroll
    for (int mt = 0; mt < 2; ++mt) {
        lS[mt] = (f32x4){0.f, 0.f, 0.f, 0.f};
        lB[mt] = (f32x4){0.f, 0.f, 0.f, 0.f};
#pragma unroll
        for (int j = 0; j < 4; ++j) {
            oS[mt][j] = (f32x4){0.f, 0.f, 0.f, 0.f};
            oB[mt][j] = (f32x4){0.f, 0.f, 0.f, 0.f};
        }
    }

    auto TILE = [&](bf16x8 (&qf)[2][2], f32x4 (&oa)[2][4], f32x4 (&la)[2],
                    bf16x8 (&kf)[4][2], bf16x8 (&vf)[4][2], int qt, int kt, bool domask) {
#pragma unroll
        for (int mt = 0; mt < 2; ++mt) {
            f32x4 sc[4];
            __builtin_amdgcn_s_setprio(1);
#pragma unroll
            for (int ct = 0; ct < 4; ++ct) {
                f32x4 z = (f32x4){0.f, 0.f, 0.f, 0.f};
                z = MFMA16(qf[mt][0], kf[ct][0], z);
                z = MFMA16(qf[mt][1], kf[ct][1], z);
                sc[ct] = z;
            }
            __builtin_amdgcn_s_setprio(0);
            if (domask) {        // diagonal region: causal mask (absolute indices)
                int qrow0 = qt * 32 + mt * 16 + quad * 4;
#pragma unroll
                for (int ct = 0; ct < 4; ++ct)
#pragma unroll
                    for (int r = 0; r < 4; ++r)
                        if (kt * 64 + ct * 16 + lo > qrow0 + r) sc[ct][r] = -INFINITY;
            }
            // bare exp2 (scores bounded); masked -> 2^-inf = 0
#pragma unroll
            for (int ct = 0; ct < 4; ++ct)
#pragma unroll
                for (int r = 0; r < 4; ++r)
                    sc[ct][r] = __builtin_amdgcn_exp2f(sc[ct][r]);

            // P: C-layout -> LDS (wave-private, stride 68: conflict-free)
#pragma unroll
            for (int ct = 0; ct < 4; ++ct)
#pragma unroll
                for (int r = 0; r < 4; ++r)
                    sPw[(quad * 4 + r) * 68 + ct * 16 + lo] = to_bf(sc[ct][r]);

            bf16x8 pf0 = *(const bf16x8*)&sPw[lo * 68 + quad * 8];
            bf16x8 pf1 = *(const bf16x8*)&sPw[lo * 68 + 32 + quad * 8];

            __builtin_amdgcn_s_setprio(1);
            // row-sum l via ones-MFMA (every output column = rowsum, C-layout)
            la[mt] = MFMA16(pf0, vone, la[mt]);
            la[mt] = MFMA16(pf1, vone, la[mt]);

#pragma unroll
            for (int nt2 = 0; nt2 < 4; ++nt2) {
                f32x4 oo = oa[mt][nt2];
                oo = MFMA16(pf0, vf[nt2][0], oo);
                oo = MFMA16(pf1, vf[nt2][1], oo);
                oa[mt][nt2] = oo;
            }
            __builtin_amdgcn_s_setprio(0);
        }
    };

    // ---- prologue: stage tile 0 ----
    STAGE(0, 0);
    __syncthreads();                 // drains vmcnt(0): buffer 0 complete

    int cur = 0;
    for (int kt = 0; kt < nt; ++kt) {
        if (kt + 1 < nt) STAGE(cur ^ 1, kt + 1);   // issue-early, in flight during compute

        // K/V fragments from LDS (swizzled read addresses), shared by both tiles
        bf16x8 kf[4][2], vf[4][2];
        const char* sKc = (const char*)sK[cur];
        const char* sVc = (const char*)sV[cur];
#pragma unroll
        for (int tt = 0; tt < 4; ++tt) {
            int krow = tt * 16 + lo;
            int rsw = (krow & 7) << 4;
#pragma unroll
            for (int h2 = 0; h2 < 2; ++h2) {
                int boff = (krow << 7) + (((h2 << 6) | (quad << 4)) ^ rsw);
                kf[tt][h2] = *(const bf16x8*)(sKc + boff);
                vf[tt][h2] = *(const bf16x8*)(sVc + boff);
            }
        }

        TILE(qfB, oB, lB, kf, vf, qtB, kt, kt == nt - 1);
        if (kt <= ktmaxS)
            TILE(qfS, oS, lS, kf, vf, qtS, kt, kt == ktmaxS);

        __syncthreads();             // staged buffer landed; all waves done with cur
        cur ^= 1;
    }

    // ---- epilogue: write both tiles ----
#pragma unroll
    for (int mt = 0; mt < 2; ++mt)
#pragma unroll
        for (int r = 0; r < 4; ++r) {
            float invS = 1.0f / lS[mt][r];
            float invB = 1.0f / lB[mt][r];
            int rowS = qtS * 32 + mt * 16 + quad * 4 + r;
            int rowB = qtB * 32 + mt * 16 + quad * 4 + r;
#pragma unroll
            for (int nt2 = 0; nt2 < 4; ++nt2) {
                ctx[((size_t)(b * 2048 + rowS)) * 2048 + h * 64 + nt2 * 16 + lo] = to_bf(oS[mt][nt2][r] * invS);
                ctx[((size_t)(b * 2048 + rowB)) * 2048 + h * 64 + nt2 * 16 + lo] = to_bf(oB[mt][nt2][r] * invB);
            }
        }
}

// ---------------- launch ----------------
extern "C" void kernel_launch(void* const* d_in, const int* in_sizes, int n_in,
                              void* d_out, int out_size, void* d_ws, size_t ws_size,
                              hipStream_t stream)
{
    (void)in_sizes; (void)n_in; (void)out_size; (void)ws_size;
    const float* x       = (const float*)d_in[0];
    // d_in[1] = mask: ignored (causal mask recomputed analytically)
    const float* cosb    = (const float*)d_in[2];
    const float* sinb    = (const float*)d_in[3];
    const float* Wq      = (const float*)d_in[4];
    const float* Wk      = (const float*)d_in[5];
    const float* Wv      = (const float*)d_in[6];
    const float* Wo      = (const float*)d_in[7];
    const float* q_scale = (const float*)d_in[8];
    const float* k_scale = (const float*)d_in[9];

    float* out   = (float*)d_out;                 // (2,2048,2048)
    float* k_out = out + 8388608;                 // (2,8,2048,64)
    float* v_out = k_out + 2097152;               // (2,8,2048,64)

    char* ws = (char*)d_ws;
    size_t off = 0;
    auto alloc = [&](size_t bytes) {
        char* p = ws + off; off += (bytes + 255) & ~(size_t)255; return p;
    };
    unsigned short* x_bf   = (unsigned short*)alloc(4096ull * 2048 * 2);   // 16 MB
    unsigned short* Wqkvt  = (unsigned short*)alloc(3072ull * 2048 * 2);   // 12 MB
    unsigned short* Wot    = (unsigned short*)alloc(2048ull * 2048 * 2);   //  8 MB
    unsigned short* qkv    = (unsigned short*)alloc(4096ull * 3072 * 2);   // 24 MB
    unsigned short* q_attn = (unsigned short*)alloc(4096ull * 2048 * 2);   // 16 MB
    unsigned short* k_attn = (unsigned short*)alloc(2048ull * 2048 * 2);   //  4 MB
    unsigned short* vt     = (unsigned short*)alloc(2097152ull * 2);       //  4 MB
    unsigned short* ctx    = (unsigned short*)alloc(4096ull * 2048 * 2);   // 16 MB

    cast_x_kernel<<<8192, 256, 0, stream>>>(x, x_bf, 8388608);
    castT_kernel<<<1024, 256, 0, stream>>>(Wq, Wqkvt, 2048);
    castT_kernel<<<256, 256, 0, stream>>>(Wk, Wqkvt + 2048ull * 2048, 512);
    castT_kernel<<<256, 256, 0, stream>>>(Wv, Wqkvt + 2560ull * 2048, 512);
    castT_kernel<<<1024, 256, 0, stream>>>(Wo, Wot, 2048);

    // qkv = x @ [Wq|Wk|Wv]  (bf16 out)
    gemm_bt<<<dim3(24, 32), 256, 0, stream>>>(x_bf, Wqkvt, nullptr, qkv, 4096, 3072, 2048);

    rmsrope_kernel<<<49152, 256, 0, stream>>>(qkv, cosb, sinb, q_scale, k_scale,
                                              q_attn, k_attn, k_out, v_out);
    vtrans_kernel<<<512, 256, 0, stream>>>(qkv, vt);

    attn_kernel<<<512, 256, 0, stream>>>(q_attn, k_attn, vt, ctx);

    // out = ctx @ Wo  (fp32 out)
    gemm_bt<<<dim3(16, 32), 256, 0, stream>>>(ctx, Wot, out, nullptr, 4096, 2048, 2048);
}

// Round 6
// 410.990 us; speedup vs baseline: 1.1200x; 1.0606x over previous
//
#include <hip/hip_runtime.h>

typedef __bf16 bf16_t;
typedef bf16_t bf16x8 __attribute__((ext_vector_type(8)));
typedef float f32x4 __attribute__((ext_vector_type(4)));

#define MFMA16(a, b, c) __builtin_amdgcn_mfma_f32_16x16x32_bf16(a, b, c, 0, 0, 0)

__device__ __forceinline__ unsigned short f2bf(float f) {
    union { float f; unsigned u; } v; v.f = f;
    unsigned r = v.u + 0x7FFFu + ((v.u >> 16) & 1u);  // RNE
    return (unsigned short)(r >> 16);
}
__device__ __forceinline__ float bf2f(unsigned short h) {
    union { unsigned u; float f; } v; v.u = ((unsigned)h) << 16;
    return v.f;
}
__device__ __forceinline__ unsigned short to_bf(float f) {
    bf16_t b = (bf16_t)f;                 // gfx950 native v_cvt (RNE)
    return __builtin_bit_cast(unsigned short, b);
}

// async global->LDS, 16B per lane; LDS dst is wave-uniform base + lane*16,
// global src address is per-lane.
__device__ __forceinline__ void gll16(const unsigned short* g, unsigned short* l) {
    __builtin_amdgcn_global_load_lds(
        (const __attribute__((address_space(1))) unsigned int*)g,
        (__attribute__((address_space(3))) unsigned int*)l, 16, 0, 0);
}

// ---------------- cast kernels ----------------
__global__ __launch_bounds__(256) void cast_x_kernel(const float* __restrict__ src,
                                                     unsigned short* __restrict__ dst, int n) {
    int i = (blockIdx.x * 256 + threadIdx.x) * 4;
    if (i >= n) return;
    float4 v = *(const float4*)&src[i];
    union { unsigned short e[4]; uint2 u; } p;
    p.e[0] = f2bf(v.x); p.e[1] = f2bf(v.y); p.e[2] = f2bf(v.z); p.e[3] = f2bf(v.w);
    *(uint2*)&dst[i] = p.u;
}

// src is K x N row-major fp32 (K=2048); dst is N x K row-major bf16 (B^T).
// LDS-tiled 64x64 transpose: coalesced reads AND writes.
__global__ __launch_bounds__(256) void castT_kernel(const float* __restrict__ src,
                                                    unsigned short* __restrict__ dst,
                                                    int N) {
    __shared__ __align__(16) unsigned short sT[64 * 68];
    int nt = blockIdx.x >> 5;            // K/64 == 32 (K fixed at 2048)
    int kt = blockIdx.x & 31;
    int k0 = kt * 64, n0 = nt * 64;
    int t = threadIdx.x;
#pragma unroll
    for (int c = t; c < 1024; c += 256) {
        int r = c >> 4, c4 = c & 15;
        float4 v = *(const float4*)&src[(size_t)(k0 + r) * N + n0 + c4 * 4];
        union { unsigned short e[4]; uint2 u; } p;
        p.e[0] = f2bf(v.x); p.e[1] = f2bf(v.y); p.e[2] = f2bf(v.z); p.e[3] = f2bf(v.w);
        *(uint2*)&sT[r * 68 + c4 * 4] = p.u;   // sT[k-row][n-col]
    }
    __syncthreads();
#pragma unroll
    for (int c = t; c < 512; c += 256) {
        int n = c >> 3, cb = c & 7;
        union { unsigned short e[8]; uint4 v; } u;
#pragma unroll
        for (int j = 0; j < 8; ++j) u.e[j] = sT[(cb * 8 + j) * 68 + n];
        *(uint4*)&dst[(size_t)(n0 + n) * 2048 + k0 + cb * 8] = u.v;
    }
}

// ---------------- GEMM: C(MxN) = A(MxK,bf16) * Bt(NxK,bf16)^T ----------------
// m97 structure: global_load_lds width=16 staging, unpadded stride-64 LDS.
__global__ __launch_bounds__(256) void gemm_bt(
    const unsigned short* __restrict__ A,
    const unsigned short* __restrict__ Bt,
    float* __restrict__ Cf, unsigned short* __restrict__ Cb,
    int M, int N, int K)
{
    __shared__ __align__(16) unsigned short sA[128 * 64];
    __shared__ __align__(16) unsigned short sB[128 * 64];
    int n0 = blockIdx.x * 128, m0 = blockIdx.y * 128;
    int tid = threadIdx.x;
    int lane = tid & 63, w = tid >> 6;
    int wm = (w >> 1) * 64, wn = (w & 1) * 64;
    int lo = lane & 15, quad = lane >> 4;

    // wave w stages rows [w*32, w*32+32): 4 chunks of 8 rows x 64 cols (1024 B)
    int srow = w * 32 + (lane >> 3);
    int scol = (lane & 7) * 8;
    const unsigned short* Ag = &A[(size_t)(m0 + srow) * K + scol];
    const unsigned short* Bg = &Bt[(size_t)(n0 + srow) * K + scol];

    f32x4 acc[4][4];
#pragma unroll
    for (int i = 0; i < 4; ++i)
#pragma unroll
        for (int j = 0; j < 4; ++j) acc[i][j] = (f32x4){0.f, 0.f, 0.f, 0.f};

    for (int kt = 0; kt < K; kt += 64) {
#pragma unroll
        for (int c = 0; c < 4; ++c) {
            gll16(Ag + (size_t)(c * 8) * K + kt, &sA[(w * 4 + c) * 512]);
            gll16(Bg + (size_t)(c * 8) * K + kt, &sB[(w * 4 + c) * 512]);
        }
        __syncthreads();
#pragma unroll
        for (int ks = 0; ks < 64; ks += 32) {
            bf16x8 af[4], bfr[4];
#pragma unroll
            for (int mi = 0; mi < 4; ++mi)
                af[mi] = *(const bf16x8*)&sA[(wm + mi * 16 + lo) * 64 + ks + quad * 8];
#pragma unroll
            for (int ni = 0; ni < 4; ++ni)
                bfr[ni] = *(const bf16x8*)&sB[(wn + ni * 16 + lo) * 64 + ks + quad * 8];
#pragma unroll
            for (int mi = 0; mi < 4; ++mi)
#pragma unroll
                for (int ni = 0; ni < 4; ++ni)
                    acc[mi][ni] = MFMA16(af[mi], bfr[ni], acc[mi][ni]);
        }
        __syncthreads();
    }

#pragma unroll
    for (int mi = 0; mi < 4; ++mi)
#pragma unroll
        for (int ni = 0; ni < 4; ++ni)
#pragma unroll
            for (int r = 0; r < 4; ++r) {
                int row = m0 + wm + mi * 16 + quad * 4 + r;
                int col = n0 + wn + ni * 16 + lo;
                if (Cf) Cf[(size_t)row * N + col] = acc[mi][ni][r];
                else    Cb[(size_t)row * N + col] = f2bf(acc[mi][ni][r]);
            }
}

// ---------------- RMSNorm + RoPE (+ scatter to outputs) ----------------
// qkv: (B*S, 3072) bf16 rows = [q 2048 | k 512 | v 512]
__global__ __launch_bounds__(256) void rmsrope_kernel(
    const unsigned short* __restrict__ qkv,
    const float* __restrict__ cosb, const float* __restrict__ sinb,
    const float* __restrict__ q_scale, const float* __restrict__ k_scale,
    unsigned short* __restrict__ q_attn, unsigned short* __restrict__ k_attn,
    float* __restrict__ k_out, float* __restrict__ v_out)
{
    int wid = blockIdx.x * 4 + (threadIdx.x >> 6);   // one wave per 64-elem row
    int lane = threadIdx.x & 63;
    int t = wid % 48;          // 0..31 q-head, 32..39 k-group, 40..47 v-group
    int bs = wid / 48;         // 0..4095
    int b = bs >> 11, s = bs & 2047;

    if (t >= 40) {             // v: straight copy to output (b,g,s,d) fp32
        int g = t - 40;
        float val = bf2f(qkv[(size_t)bs * 3072 + 2560 + g * 64 + lane]);
        v_out[(size_t)((b * 8 + g) * 2048 + s) * 64 + lane] = val;
        return;
    }
    bool is_q = (t < 32);
    int col = is_q ? (t * 64) : (2048 + (t - 32) * 64);
    float val = bf2f(qkv[(size_t)bs * 3072 + col + lane]);
    float ss = val * val;
#pragma unroll
    for (int m = 1; m < 64; m <<= 1) ss += __shfl_xor(ss, m);
    float rs = rsqrtf(ss * (1.0f / 64.0f) + 1e-6f);
    float scl = is_q ? q_scale[lane] : k_scale[lane];
    float xn = val * rs * scl;
    float other = __shfl_xor(xn, 32);
    float rot = (lane < 32) ? -other : other;     // [-x2, x1]
    float o = xn * cosb[s * 64 + lane] + rot * sinb[s * 64 + lane];
    if (is_q) {
        // fold 1/sqrt(D)=0.125 and log2(e) into q (attention works in exp2 domain)
        q_attn[(size_t)((b * 32 + t) * 2048 + s) * 64 + lane] = to_bf(o * (0.125f * 1.44269504f));
    } else {
        int g = t - 32;
        size_t idx = (size_t)((b * 8 + g) * 2048 + s) * 64 + lane;
        k_attn[idx] = to_bf(o);
        k_out[idx] = o;
    }
}

// ---------------- V transpose: qkv v-cols -> vt (b,g,d,s) bf16 ----------------
__global__ __launch_bounds__(256) void vtrans_kernel(
    const unsigned short* __restrict__ qkv, unsigned short* __restrict__ vt)
{
    __shared__ __align__(16) unsigned short sT[64 * 68];
    int idx = blockIdx.x;            // B*G*32 = 512
    int st = idx & 31, g = (idx >> 5) & 7, b = idx >> 8;
    int tid = threadIdx.x;
#pragma unroll
    for (int c = tid; c < 512; c += 256) {
        int r = c >> 3, cb = c & 7;
        *(uint4*)&sT[r * 68 + cb * 8] =
            *(const uint4*)&qkv[(size_t)(b * 2048 + st * 64 + r) * 3072 + 2560 + g * 64 + cb * 8];
    }
    __syncthreads();
#pragma unroll
    for (int c = tid; c < 512; c += 256) {
        int d = c >> 3, cb = c & 7;
        union { unsigned short e[8]; uint4 v; } u;
#pragma unroll
        for (int j = 0; j < 8; ++j) u.e[j] = sT[(cb * 8 + j) * 68 + d];
        *(uint4*)&vt[((size_t)(b * 8 + g) * 64 + d) * 2048 + st * 64 + cb * 8] = u.v;
    }
}

// ---------------- flash attention, causal, GQA ----------------
// R5 post-mortem: LDS-shared K/V staging worked (134->110us) but registers
// exploded (140 arch + ~80 acc + ~64 bulk fragments + 32 Q = >250/wave ->
// 1 wave/SIMD, ~1 block/CU, occupancy 10%). THIS version reclaims residency:
//   - fragments read JUST-IN-TIME from LDS (2 ds_read_b128 right before the
//     2 MFMAs that consume them) — kills the 64-VGPR bulk kf/vf arrays. LDS
//     is far from saturated (0 conflicts), extra reads are free.
//   - ONE q-tile per block (no pair-riding) — halves accumulators. 1024
//     blocks, qt descending so long tasks dispatch first, short backfill.
//   - __launch_bounds__(256, 2) caps unified regs at 256 (>=2 waves/SIMD).
// LDS 40.5KB -> 3 blocks/CU cap; grid offers 4/CU. Same verified staging
// swizzle as R5 (rule #21: linear LDS dest + inverse-swizzled global source +
// swizzled read). blockIdx&7==g pins (b,g) K/V per XCD.
__global__ __launch_bounds__(256, 2) void attn_kernel(
    const unsigned short* __restrict__ q_attn,   // (b,h,s,d) bf16, pre-scaled (log2 domain)
    const unsigned short* __restrict__ k_attn,   // (b,g,s,d) bf16 post-rope
    const unsigned short* __restrict__ vt,       // (b,g,d,s) bf16
    unsigned short* __restrict__ ctx)            // (b,s,h*d) bf16
{
    __shared__ __align__(16) unsigned short sK[2][4096];   // 16 KB (2 x 64x64 bf16)
    __shared__ __align__(16) unsigned short sV[2][4096];   // 16 KB
    __shared__ __align__(16) unsigned short sP[4][16 * 68];// 8.5 KB (wave-private)

    int w = threadIdx.x >> 6;        // wave in block = head-in-group, 0..3
    int lane = threadIdx.x & 63;

    int g = blockIdx.x & 7;          // XCD swizzle: (b,g) working set pinned per XCD
    int ord = blockIdx.x >> 3;       // 0..127
    int b = ord & 1;
    int qt = 63 - (ord >> 1);        // 63..0: longest tasks dispatched first
    int h = g * 4 + w;

    int lo = lane & 15, quad = lane >> 4;
    unsigned short* sPw = sP[w];

    const unsigned short* Qb = q_attn + (size_t)(b * 32 + h) * 2048 * 64;
    const unsigned short* Kb = k_attn + (size_t)(b * 8 + g) * 2048 * 64;
    const unsigned short* Vb = vt + (size_t)(b * 8 + g) * 64 * 2048;

    int nt = (qt >> 1) + 1;          // kv tiles 0..nt-1 (tile = 64 kv)

    // staging lane geometry: chunk = 8 rows x 64 cols (1 KB); lane l covers
    // row rsub of the chunk at inverse-swizzled column csw (rule #21).
    int rsub = lane >> 3;                  // 0..7 (== row & 7 within chunk)
    int csw  = ((lane & 7) ^ rsub) << 3;   // ushort units

    auto STAGE = [&](int buf, int kt) {
#pragma unroll
        for (int i = 0; i < 2; ++i) {
            int c = w + i * 4;             // this wave's chunks: w, w+4
            gll16(Kb + (size_t)(kt * 64 + c * 8 + rsub) * 64 + csw, &sK[buf][c * 512]);
            gll16(Vb + (size_t)(c * 8 + rsub) * 2048 + kt * 64 + csw, &sV[buf][c * 512]);
        }
    };

    const bf16_t one = (bf16_t)1.0f;
    const bf16x8 vone = {one, one, one, one, one, one, one, one};

    // Q fragments held in registers for the whole sweep (16 VGPR)
    bf16x8 qf[2][2];
#pragma unroll
    for (int mt = 0; mt < 2; ++mt)
#pragma unroll
        for (int h2 = 0; h2 < 2; ++h2)
            qf[mt][h2] = *(const bf16x8*)&Qb[(size_t)(qt * 32 + mt * 16 + lo) * 64 + h2 * 32 + quad * 8];

    f32x4 o_acc[2][4];
    f32x4 l_acc[2];
#pragma unroll
    for (int mt = 0; mt < 2; ++mt) {
        l_acc[mt] = (f32x4){0.f, 0.f, 0.f, 0.f};
#pragma unroll
        for (int j = 0; j < 4; ++j) o_acc[mt][j] = (f32x4){0.f, 0.f, 0.f, 0.f};
    }

    // ---- prologue: stage tile 0 ----
    STAGE(0, 0);
    __syncthreads();                 // drains vmcnt(0): buffer 0 complete

    int cur = 0;
    for (int kt = 0; kt < nt; ++kt) {
        if (kt + 1 < nt) STAGE(cur ^ 1, kt + 1);   // issue-early, in flight during compute

        const char* sKc = (const char*)sK[cur];
        const char* sVc = (const char*)sV[cur];
        bool domask = (kt == nt - 1);

#pragma unroll
        for (int mt = 0; mt < 2; ++mt) {
            // S tile: 16 q-rows x 64 kv — K fragments read JIT from LDS
            f32x4 sc[4];
            __builtin_amdgcn_s_setprio(1);
#pragma unroll
            for (int ct = 0; ct < 4; ++ct) {
                int krow = ct * 16 + lo;
                int rsw = (krow & 7) << 4;
                bf16x8 kf0 = *(const bf16x8*)(sKc + (krow << 7) + (((quad << 4)) ^ rsw));
                bf16x8 kf1 = *(const bf16x8*)(sKc + (krow << 7) + (((1 << 6) | (quad << 4)) ^ rsw));
                f32x4 z = (f32x4){0.f, 0.f, 0.f, 0.f};
                z = MFMA16(qf[mt][0], kf0, z);
                z = MFMA16(qf[mt][1], kf1, z);
                sc[ct] = z;
            }
            __builtin_amdgcn_s_setprio(0);
            if (domask) {        // diagonal region: causal mask (absolute indices)
                int qrow0 = qt * 32 + mt * 16 + quad * 4;
#pragma unroll
                for (int ct = 0; ct < 4; ++ct)
#pragma unroll
                    for (int r = 0; r < 4; ++r)
                        if (kt * 64 + ct * 16 + lo > qrow0 + r) sc[ct][r] = -INFINITY;
            }
            // bare exp2 (scores bounded); masked -> 2^-inf = 0
#pragma unroll
            for (int ct = 0; ct < 4; ++ct)
#pragma unroll
                for (int r = 0; r < 4; ++r)
                    sc[ct][r] = __builtin_amdgcn_exp2f(sc[ct][r]);

            // P: C-layout -> LDS (wave-private, stride 68: conflict-free)
#pragma unroll
            for (int ct = 0; ct < 4; ++ct)
#pragma unroll
                for (int r = 0; r < 4; ++r)
                    sPw[(quad * 4 + r) * 68 + ct * 16 + lo] = to_bf(sc[ct][r]);

            bf16x8 pf0 = *(const bf16x8*)&sPw[lo * 68 + quad * 8];
            bf16x8 pf1 = *(const bf16x8*)&sPw[lo * 68 + 32 + quad * 8];

            __builtin_amdgcn_s_setprio(1);
            // row-sum l via ones-MFMA (every output column = rowsum, C-layout)
            l_acc[mt] = MFMA16(pf0, vone, l_acc[mt]);
            l_acc[mt] = MFMA16(pf1, vone, l_acc[mt]);

            // PV: V fragments read JIT from LDS
#pragma unroll
            for (int nt2 = 0; nt2 < 4; ++nt2) {
                int vrow = nt2 * 16 + lo;
                int rsw = (vrow & 7) << 4;
                bf16x8 vf0 = *(const bf16x8*)(sVc + (vrow << 7) + (((quad << 4)) ^ rsw));
                bf16x8 vf1 = *(const bf16x8*)(sVc + (vrow << 7) + (((1 << 6) | (quad << 4)) ^ rsw));
                f32x4 oo = o_acc[mt][nt2];
                oo = MFMA16(pf0, vf0, oo);
                oo = MFMA16(pf1, vf1, oo);
                o_acc[mt][nt2] = oo;
            }
            __builtin_amdgcn_s_setprio(0);
        }

        __syncthreads();             // staged buffer landed; all waves done with cur
        cur ^= 1;
    }

    // ---- epilogue ----
#pragma unroll
    for (int mt = 0; mt < 2; ++mt)
#pragma unroll
        for (int r = 0; r < 4; ++r) {
            float inv = 1.0f / l_acc[mt][r];
            int row = qt * 32 + mt * 16 + quad * 4 + r;
#pragma unroll
            for (int nt2 = 0; nt2 < 4; ++nt2) {
                size_t oi = ((size_t)(b * 2048 + row)) * 2048 + h * 64 + nt2 * 16 + lo;
                ctx[oi] = to_bf(o_acc[mt][nt2][r] * inv);
            }
        }
}

// ---------------- launch ----------------
extern "C" void kernel_launch(void* const* d_in, const int* in_sizes, int n_in,
                              void* d_out, int out_size, void* d_ws, size_t ws_size,
                              hipStream_t stream)
{
    (void)in_sizes; (void)n_in; (void)out_size; (void)ws_size;
    const float* x       = (const float*)d_in[0];
    // d_in[1] = mask: ignored (causal mask recomputed analytically)
    const float* cosb    = (const float*)d_in[2];
    const float* sinb    = (const float*)d_in[3];
    const float* Wq      = (const float*)d_in[4];
    const float* Wk      = (const float*)d_in[5];
    const float* Wv      = (const float*)d_in[6];
    const float* Wo      = (const float*)d_in[7];
    const float* q_scale = (const float*)d_in[8];
    const float* k_scale = (const float*)d_in[9];

    float* out   = (float*)d_out;                 // (2,2048,2048)
    float* k_out = out + 8388608;                 // (2,8,2048,64)
    float* v_out = k_out + 2097152;               // (2,8,2048,64)

    char* ws = (char*)d_ws;
    size_t off = 0;
    auto alloc = [&](size_t bytes) {
        char* p = ws + off; off += (bytes + 255) & ~(size_t)255; return p;
    };
    unsigned short* x_bf   = (unsigned short*)alloc(4096ull * 2048 * 2);   // 16 MB
    unsigned short* Wqkvt  = (unsigned short*)alloc(3072ull * 2048 * 2);   // 12 MB
    unsigned short* Wot    = (unsigned short*)alloc(2048ull * 2048 * 2);   //  8 MB
    unsigned short* qkv    = (unsigned short*)alloc(4096ull * 3072 * 2);   // 24 MB
    unsigned short* q_attn = (unsigned short*)alloc(4096ull * 2048 * 2);   // 16 MB
    unsigned short* k_attn = (unsigned short*)alloc(2048ull * 2048 * 2);   //  4 MB
    unsigned short* vt     = (unsigned short*)alloc(2097152ull * 2);       //  4 MB
    unsigned short* ctx    = (unsigned short*)alloc(4096ull * 2048 * 2);   // 16 MB

    cast_x_kernel<<<8192, 256, 0, stream>>>(x, x_bf, 8388608);
    castT_kernel<<<1024, 256, 0, stream>>>(Wq, Wqkvt, 2048);
    castT_kernel<<<256, 256, 0, stream>>>(Wk, Wqkvt + 2048ull * 2048, 512);
    castT_kernel<<<256, 256, 0, stream>>>(Wv, Wqkvt + 2560ull * 2048, 512);
    castT_kernel<<<1024, 256, 0, stream>>>(Wo, Wot, 2048);

    // qkv = x @ [Wq|Wk|Wv]  (bf16 out)
    gemm_bt<<<dim3(24, 32), 256, 0, stream>>>(x_bf, Wqkvt, nullptr, qkv, 4096, 3072, 2048);

    rmsrope_kernel<<<49152, 256, 0, stream>>>(qkv, cosb, sinb, q_scale, k_scale,
                                              q_attn, k_attn, k_out, v_out);
    vtrans_kernel<<<512, 256, 0, stream>>>(qkv, vt);

    attn_kernel<<<1024, 256, 0, stream>>>(q_attn, k_attn, vt, ctx);

    // out = ctx @ Wo  (fp32 out)
    gemm_bt<<<dim3(16, 32), 256, 0, stream>>>(ctx, Wot, out, nullptr, 4096, 2048, 2048);
}

// Round 7
// 396.215 us; speedup vs baseline: 1.1617x; 1.0373x over previous
//
#include <hip/hip_runtime.h>

typedef __bf16 bf16_t;
typedef bf16_t bf16x8 __attribute__((ext_vector_type(8)));
typedef float f32x4 __attribute__((ext_vector_type(4)));

#define MFMA16(a, b, c) __builtin_amdgcn_mfma_f32_16x16x32_bf16(a, b, c, 0, 0, 0)

__device__ __forceinline__ unsigned short f2bf(float f) {
    union { float f; unsigned u; } v; v.f = f;
    unsigned r = v.u + 0x7FFFu + ((v.u >> 16) & 1u);  // RNE
    return (unsigned short)(r >> 16);
}
__device__ __forceinline__ float bf2f(unsigned short h) {
    union { unsigned u; float f; } v; v.u = ((unsigned)h) << 16;
    return v.f;
}
__device__ __forceinline__ unsigned short to_bf(float f) {
    bf16_t b = (bf16_t)f;                 // gfx950 native v_cvt (RNE)
    return __builtin_bit_cast(unsigned short, b);
}

// async global->LDS, 16B per lane; LDS dst is wave-uniform base + lane*16,
// global src address is per-lane.
__device__ __forceinline__ void gll16(const unsigned short* g, unsigned short* l) {
    __builtin_amdgcn_global_load_lds(
        (const __attribute__((address_space(1))) unsigned int*)g,
        (__attribute__((address_space(3))) unsigned int*)l, 16, 0, 0);
}

// ---------------- cast kernels ----------------
__global__ __launch_bounds__(256) void cast_x_kernel(const float* __restrict__ src,
                                                     unsigned short* __restrict__ dst, int n) {
    int i = (blockIdx.x * 256 + threadIdx.x) * 4;
    if (i >= n) return;
    float4 v = *(const float4*)&src[i];
    union { unsigned short e[4]; uint2 u; } p;
    p.e[0] = f2bf(v.x); p.e[1] = f2bf(v.y); p.e[2] = f2bf(v.z); p.e[3] = f2bf(v.w);
    *(uint2*)&dst[i] = p.u;
}

// src is K x N row-major fp32 (K=2048); dst is N x K row-major bf16 (B^T).
__global__ __launch_bounds__(256) void castT_kernel(const float* __restrict__ src,
                                                    unsigned short* __restrict__ dst,
                                                    int N) {
    __shared__ __align__(16) unsigned short sT[64 * 68];
    int nt = blockIdx.x >> 5;            // K/64 == 32 (K fixed at 2048)
    int kt = blockIdx.x & 31;
    int k0 = kt * 64, n0 = nt * 64;
    int t = threadIdx.x;
#pragma unroll
    for (int c = t; c < 1024; c += 256) {
        int r = c >> 4, c4 = c & 15;
        float4 v = *(const float4*)&src[(size_t)(k0 + r) * N + n0 + c4 * 4];
        union { unsigned short e[4]; uint2 u; } p;
        p.e[0] = f2bf(v.x); p.e[1] = f2bf(v.y); p.e[2] = f2bf(v.z); p.e[3] = f2bf(v.w);
        *(uint2*)&sT[r * 68 + c4 * 4] = p.u;   // sT[k-row][n-col]
    }
    __syncthreads();
#pragma unroll
    for (int c = t; c < 512; c += 256) {
        int n = c >> 3, cb = c & 7;
        union { unsigned short e[8]; uint4 v; } u;
#pragma unroll
        for (int j = 0; j < 8; ++j) u.e[j] = sT[(cb * 8 + j) * 68 + n];
        *(uint4*)&dst[(size_t)(n0 + n) * 2048 + k0 + cb * 8] = u.v;
    }
}

// ---------------- GEMM: 256x256 tile, 8-phase counted-vmcnt schedule ----------
// C(MxN) = A(MxK,bf16) * Bt(NxK,bf16)^T.  8 waves (2M x 4N), BK=64, dbuf LDS
// 128 KB. Per phase: 12 ds_read_b128 + 2 gll16 (one 16KB stage-unit across the
// block) + barrier + 16 MFMA + vmcnt(6) + barrier.  Stage-unit schedule (tile
// parity = buffer parity; T=2i even tile in buf0, computed p1-p4; odd in buf1,
// p5-p8):
//   p1: A-u1(2i+1)->b1   p2: B-u1(2i+1)->b1   p3: A-u0(2i+2)->b0
//   p4: B-u0(2i+2)->b0   p5: A-u1(2i+2)->b0   p6: B-u1(2i+2)->b0
//   p7: A-u0(2i+3)->b1   p8: B-u0(2i+3)->b1
// Every unit: staged >=1 phase after its region's last read (no overwrite
// hazard under barrier lockstep) and consumed >=4 phases after staging, which
// per-phase vmcnt(6) (3 units in flight) + barrier makes visible cross-wave.
// Read swizzle: 16B-unit u ^= (row&7); staged via inverse-swizzled global
// source (rule #21) so gll16's linear dest stays legal.
__global__ __launch_bounds__(512) void gemm256_bt(
    const unsigned short* __restrict__ A,
    const unsigned short* __restrict__ Bt,
    float* __restrict__ Cf, unsigned short* __restrict__ Cb,
    int M, int N, int K)
{
    extern __shared__ unsigned short lds[];   // [2][A 16384 | B 16384] ushorts = 131072 B
    const int KT = K >> 6;                    // 64-wide K-tiles (32 for K=2048)
    const int NIT = KT >> 1;                  // 8-phase iterations (16)

    int tid = threadIdx.x;
    int lane = tid & 63, w = tid >> 6;        // 8 waves
    int wmi = w >> 2, wni = w & 3;            // wave m-half (0..1), n-quarter (0..3)
    int lo = lane & 15, quad = lane >> 4;
    int m0 = blockIdx.y * 256, n0 = blockIdx.x * 256;

    // staging lane geometry (inverse-swizzled source)
    int rsub = lane >> 3;                     // 0..7  (row & 7 within 8-row chunk)
    int csw  = ((lane & 7) ^ rsub) << 3;      // ushort col

    f32x4 acc[8][4];
#pragma unroll
    for (int i = 0; i < 8; ++i)
#pragma unroll
        for (int j = 0; j < 4; ++j) acc[i][j] = (f32x4){0.f, 0.f, 0.f, 0.f};

    auto stA = [&](int buf, int mp, int T) {
#pragma unroll
        for (int j = 0; j < 2; ++j) {
            int rr = (w * 2 + j) * 8 + rsub;
            gll16(A + (size_t)(m0 + mp * 128 + rr) * K + T * 64 + csw,
                  lds + buf * 32768 + mp * 8192 + (w * 2 + j) * 512);
        }
    };
    auto stB = [&](int buf, int np, int T) {
#pragma unroll
        for (int j = 0; j < 2; ++j) {
            int rr = (w * 2 + j) * 8 + rsub;
            gll16(Bt + (size_t)(n0 + np * 128 + rr) * K + T * 64 + csw,
                  lds + buf * 32768 + 16384 + np * 8192 + (w * 2 + j) * 512);
        }
    };

    auto phase = [&](int buf, int mp, int np, auto stage, bool drain) {
        // ds-loads for this quadrant (row&7 == lo&7 for all frag rows)
        bf16x8 a[4][2], b2[2][2];
#pragma unroll
        for (int mf = 0; mf < 4; ++mf)
#pragma unroll
            for (int k2 = 0; k2 < 2; ++k2) {
                int r = mp * 128 + wmi * 64 + mf * 16 + lo;
                int u = quad + k2 * 4;
                a[mf][k2] = *(const bf16x8*)&lds[buf * 32768 + r * 64 + ((u ^ (lo & 7)) << 3)];
            }
#pragma unroll
        for (int nf = 0; nf < 2; ++nf)
#pragma unroll
            for (int k2 = 0; k2 < 2; ++k2) {
                int r = np * 128 + wni * 32 + nf * 16 + lo;
                int u = quad + k2 * 4;
                b2[nf][k2] = *(const bf16x8*)&lds[buf * 32768 + 16384 + r * 64 + ((u ^ (lo & 7)) << 3)];
            }
        stage();
        __builtin_amdgcn_s_barrier();
        __builtin_amdgcn_sched_barrier(0);
        __builtin_amdgcn_s_setprio(1);
#pragma unroll
        for (int mf = 0; mf < 4; ++mf)
#pragma unroll
            for (int nf = 0; nf < 2; ++nf) {
                f32x4 z = acc[mp * 4 + mf][np * 2 + nf];
                z = MFMA16(a[mf][0], b2[nf][0], z);
                z = MFMA16(a[mf][1], b2[nf][1], z);
                acc[mp * 4 + mf][np * 2 + nf] = z;
            }
        __builtin_amdgcn_s_setprio(0);
        if (drain) asm volatile("s_waitcnt vmcnt(0)" ::: "memory");
        else       asm volatile("s_waitcnt vmcnt(6)" ::: "memory");
        __builtin_amdgcn_s_barrier();
        __builtin_amdgcn_sched_barrier(0);
    };
    auto nop = [&] {};

    // ---- prologue: tile0 fully + tile1 first two units; counted wait ----
    stA(0, 0, 0); stB(0, 0, 0); stA(0, 1, 0); stB(0, 1, 0);
    stA(1, 0, 1); stB(1, 0, 1);
    asm volatile("s_waitcnt vmcnt(4)" ::: "memory");   // tile0's 4 units landed
    __builtin_amdgcn_s_barrier();
    __builtin_amdgcn_sched_barrier(0);

    // ---- steady iterations ----
    for (int i = 0; i < NIT - 1; ++i) {
        int T1 = 2 * i + 1, T2 = 2 * i + 2, T3 = 2 * i + 3;
        phase(0, 0, 0, [&] { stA(1, 1, T1); }, false);
        phase(0, 0, 1, [&] { stB(1, 1, T1); }, false);
        phase(0, 1, 0, [&] { stA(0, 0, T2); }, false);
        phase(0, 1, 1, [&] { stB(0, 0, T2); }, false);
        phase(1, 0, 0, [&] { stA(0, 1, T2); }, false);
        phase(1, 0, 1, [&] { stB(0, 1, T2); }, false);
        phase(1, 1, 0, [&] { stA(1, 0, T3); }, false);
        phase(1, 1, 1, [&] { stB(1, 0, T3); }, false);
    }
    // ---- peeled final iteration (tiles KT-2, KT-1): no further prefetch ----
    {
        int T1 = KT - 1;
        phase(0, 0, 0, [&] { stA(1, 1, T1); }, false);
        phase(0, 0, 1, [&] { stB(1, 1, T1); }, true);   // drain: everything landed
        phase(0, 1, 0, nop, false);
        phase(0, 1, 1, nop, false);
        phase(1, 0, 0, nop, false);
        phase(1, 0, 1, nop, false);
        phase(1, 1, 0, nop, false);
        phase(1, 1, 1, nop, false);
    }

    // ---- epilogue ----
#pragma unroll
    for (int mi = 0; mi < 8; ++mi) {
        int mp = mi >> 2, mf = mi & 3;
        int row_base = m0 + mp * 128 + wmi * 64 + mf * 16 + quad * 4;
#pragma unroll
        for (int ni = 0; ni < 4; ++ni) {
            int np = ni >> 1, nf = ni & 1;
            int col = n0 + np * 128 + wni * 32 + nf * 16 + lo;
#pragma unroll
            for (int r = 0; r < 4; ++r) {
                int row = row_base + r;
                if (Cf) Cf[(size_t)row * N + col] = acc[mi][ni][r];
                else    Cb[(size_t)row * N + col] = f2bf(acc[mi][ni][r]);
            }
        }
    }
}

// ---------------- RMSNorm + RoPE (+ scatter to outputs) ----------------
// qkv: (B*S, 3072) bf16 rows = [q 2048 | k 512 | v 512]
__global__ __launch_bounds__(256) void rmsrope_kernel(
    const unsigned short* __restrict__ qkv,
    const float* __restrict__ cosb, const float* __restrict__ sinb,
    const float* __restrict__ q_scale, const float* __restrict__ k_scale,
    unsigned short* __restrict__ q_attn, unsigned short* __restrict__ k_attn,
    float* __restrict__ k_out, float* __restrict__ v_out)
{
    int wid = blockIdx.x * 4 + (threadIdx.x >> 6);   // one wave per 64-elem row
    int lane = threadIdx.x & 63;
    int t = wid % 48;          // 0..31 q-head, 32..39 k-group, 40..47 v-group
    int bs = wid / 48;         // 0..4095
    int b = bs >> 11, s = bs & 2047;

    if (t >= 40) {             // v: straight copy to output (b,g,s,d) fp32
        int g = t - 40;
        float val = bf2f(qkv[(size_t)bs * 3072 + 2560 + g * 64 + lane]);
        v_out[(size_t)((b * 8 + g) * 2048 + s) * 64 + lane] = val;
        return;
    }
    bool is_q = (t < 32);
    int col = is_q ? (t * 64) : (2048 + (t - 32) * 64);
    float val = bf2f(qkv[(size_t)bs * 3072 + col + lane]);
    float ss = val * val;
#pragma unroll
    for (int m = 1; m < 64; m <<= 1) ss += __shfl_xor(ss, m);
    float rs = rsqrtf(ss * (1.0f / 64.0f) + 1e-6f);
    float scl = is_q ? q_scale[lane] : k_scale[lane];
    float xn = val * rs * scl;
    float other = __shfl_xor(xn, 32);
    float rot = (lane < 32) ? -other : other;     // [-x2, x1]
    float o = xn * cosb[s * 64 + lane] + rot * sinb[s * 64 + lane];
    if (is_q) {
        // fold 1/sqrt(D)=0.125 and log2(e) into q (attention works in exp2 domain)
        q_attn[(size_t)((b * 32 + t) * 2048 + s) * 64 + lane] = to_bf(o * (0.125f * 1.44269504f));
    } else {
        int g = t - 32;
        size_t idx = (size_t)((b * 8 + g) * 2048 + s) * 64 + lane;
        k_attn[idx] = to_bf(o);
        k_out[idx] = o;
    }
}

// ---------------- V transpose: qkv v-cols -> vt (b,g,d,s) bf16 ----------------
__global__ __launch_bounds__(256) void vtrans_kernel(
    const unsigned short* __restrict__ qkv, unsigned short* __restrict__ vt)
{
    __shared__ __align__(16) unsigned short sT[64 * 68];
    int idx = blockIdx.x;            // B*G*32 = 512
    int st = idx & 31, g = (idx >> 5) & 7, b = idx >> 8;
    int tid = threadIdx.x;
#pragma unroll
    for (int c = tid; c < 512; c += 256) {
        int r = c >> 3, cb = c & 7;
        *(uint4*)&sT[r * 68 + cb * 8] =
            *(const uint4*)&qkv[(size_t)(b * 2048 + st * 64 + r) * 3072 + 2560 + g * 64 + cb * 8];
    }
    __syncthreads();
#pragma unroll
    for (int c = tid; c < 512; c += 256) {
        int d = c >> 3, cb = c & 7;
        union { unsigned short e[8]; uint4 v; } u;
#pragma unroll
        for (int j = 0; j < 8; ++j) u.e[j] = sT[(cb * 8 + j) * 68 + d];
        *(uint4*)&vt[((size_t)(b * 8 + g) * 64 + d) * 2048 + st * 64 + cb * 8] = u.v;
    }
}

// ---------------- flash attention, causal, GQA (R6 structure, unchanged) ----
__global__ __launch_bounds__(256, 2) void attn_kernel(
    const unsigned short* __restrict__ q_attn,   // (b,h,s,d) bf16, pre-scaled (log2 domain)
    const unsigned short* __restrict__ k_attn,   // (b,g,s,d) bf16 post-rope
    const unsigned short* __restrict__ vt,       // (b,g,d,s) bf16
    unsigned short* __restrict__ ctx)            // (b,s,h*d) bf16
{
    __shared__ __align__(16) unsigned short sK[2][4096];   // 16 KB (2 x 64x64 bf16)
    __shared__ __align__(16) unsigned short sV[2][4096];   // 16 KB
    __shared__ __align__(16) unsigned short sP[4][16 * 68];// 8.5 KB (wave-private)

    int w = threadIdx.x >> 6;        // wave in block = head-in-group, 0..3
    int lane = threadIdx.x & 63;

    int g = blockIdx.x & 7;          // XCD swizzle: (b,g) working set pinned per XCD
    int ord = blockIdx.x >> 3;       // 0..127
    int b = ord & 1;
    int qt = 63 - (ord >> 1);        // 63..0: longest tasks dispatched first
    int h = g * 4 + w;

    int lo = lane & 15, quad = lane >> 4;
    unsigned short* sPw = sP[w];

    const unsigned short* Qb = q_attn + (size_t)(b * 32 + h) * 2048 * 64;
    const unsigned short* Kb = k_attn + (size_t)(b * 8 + g) * 2048 * 64;
    const unsigned short* Vb = vt + (size_t)(b * 8 + g) * 64 * 2048;

    int nt = (qt >> 1) + 1;          // kv tiles 0..nt-1 (tile = 64 kv)

    int rsub = lane >> 3;                  // 0..7 (== row & 7 within chunk)
    int csw  = ((lane & 7) ^ rsub) << 3;   // ushort units

    auto STAGE = [&](int buf, int kt) {
#pragma unroll
        for (int i = 0; i < 2; ++i) {
            int c = w + i * 4;             // this wave's chunks: w, w+4
            gll16(Kb + (size_t)(kt * 64 + c * 8 + rsub) * 64 + csw, &sK[buf][c * 512]);
            gll16(Vb + (size_t)(c * 8 + rsub) * 2048 + kt * 64 + csw, &sV[buf][c * 512]);
        }
    };

    const bf16_t one = (bf16_t)1.0f;
    const bf16x8 vone = {one, one, one, one, one, one, one, one};

    bf16x8 qf[2][2];
#pragma unroll
    for (int mt = 0; mt < 2; ++mt)
#pragma unroll
        for (int h2 = 0; h2 < 2; ++h2)
            qf[mt][h2] = *(const bf16x8*)&Qb[(size_t)(qt * 32 + mt * 16 + lo) * 64 + h2 * 32 + quad * 8];

    f32x4 o_acc[2][4];
    f32x4 l_acc[2];
#pragma unroll
    for (int mt = 0; mt < 2; ++mt) {
        l_acc[mt] = (f32x4){0.f, 0.f, 0.f, 0.f};
#pragma unroll
        for (int j = 0; j < 4; ++j) o_acc[mt][j] = (f32x4){0.f, 0.f, 0.f, 0.f};
    }

    STAGE(0, 0);
    __syncthreads();                 // drains vmcnt(0): buffer 0 complete

    int cur = 0;
    for (int kt = 0; kt < nt; ++kt) {
        if (kt + 1 < nt) STAGE(cur ^ 1, kt + 1);   // issue-early, in flight during compute

        const char* sKc = (const char*)sK[cur];
        const char* sVc = (const char*)sV[cur];
        bool domask = (kt == nt - 1);

#pragma unroll
        for (int mt = 0; mt < 2; ++mt) {
            f32x4 sc[4];
            __builtin_amdgcn_s_setprio(1);
#pragma unroll
            for (int ct = 0; ct < 4; ++ct) {
                int krow = ct * 16 + lo;
                int rsw = (krow & 7) << 4;
                bf16x8 kf0 = *(const bf16x8*)(sKc + (krow << 7) + (((quad << 4)) ^ rsw));
                bf16x8 kf1 = *(const bf16x8*)(sKc + (krow << 7) + (((1 << 6) | (quad << 4)) ^ rsw));
                f32x4 z = (f32x4){0.f, 0.f, 0.f, 0.f};
                z = MFMA16(qf[mt][0], kf0, z);
                z = MFMA16(qf[mt][1], kf1, z);
                sc[ct] = z;
            }
            __builtin_amdgcn_s_setprio(0);
            if (domask) {
                int qrow0 = qt * 32 + mt * 16 + quad * 4;
#pragma unroll
                for (int ct = 0; ct < 4; ++ct)
#pragma unroll
                    for (int r = 0; r < 4; ++r)
                        if (kt * 64 + ct * 16 + lo > qrow0 + r) sc[ct][r] = -INFINITY;
            }
#pragma unroll
            for (int ct = 0; ct < 4; ++ct)
#pragma unroll
                for (int r = 0; r < 4; ++r)
                    sc[ct][r] = __builtin_amdgcn_exp2f(sc[ct][r]);

#pragma unroll
            for (int ct = 0; ct < 4; ++ct)
#pragma unroll
                for (int r = 0; r < 4; ++r)
                    sPw[(quad * 4 + r) * 68 + ct * 16 + lo] = to_bf(sc[ct][r]);

            bf16x8 pf0 = *(const bf16x8*)&sPw[lo * 68 + quad * 8];
            bf16x8 pf1 = *(const bf16x8*)&sPw[lo * 68 + 32 + quad * 8];

            __builtin_amdgcn_s_setprio(1);
            l_acc[mt] = MFMA16(pf0, vone, l_acc[mt]);
            l_acc[mt] = MFMA16(pf1, vone, l_acc[mt]);

#pragma unroll
            for (int nt2 = 0; nt2 < 4; ++nt2) {
                int vrow = nt2 * 16 + lo;
                int rsw = (vrow & 7) << 4;
                bf16x8 vf0 = *(const bf16x8*)(sVc + (vrow << 7) + (((quad << 4)) ^ rsw));
                bf16x8 vf1 = *(const bf16x8*)(sVc + (vrow << 7) + (((1 << 6) | (quad << 4)) ^ rsw));
                f32x4 oo = o_acc[mt][nt2];
                oo = MFMA16(pf0, vf0, oo);
                oo = MFMA16(pf1, vf1, oo);
                o_acc[mt][nt2] = oo;
            }
            __builtin_amdgcn_s_setprio(0);
        }

        __syncthreads();
        cur ^= 1;
    }

#pragma unroll
    for (int mt = 0; mt < 2; ++mt)
#pragma unroll
        for (int r = 0; r < 4; ++r) {
            float inv = 1.0f / l_acc[mt][r];
            int row = qt * 32 + mt * 16 + quad * 4 + r;
#pragma unroll
            for (int nt2 = 0; nt2 < 4; ++nt2) {
                size_t oi = ((size_t)(b * 2048 + row)) * 2048 + h * 64 + nt2 * 16 + lo;
                ctx[oi] = to_bf(o_acc[mt][nt2][r] * inv);
            }
        }
}

// ---------------- launch ----------------
extern "C" void kernel_launch(void* const* d_in, const int* in_sizes, int n_in,
                              void* d_out, int out_size, void* d_ws, size_t ws_size,
                              hipStream_t stream)
{
    (void)in_sizes; (void)n_in; (void)out_size; (void)ws_size;
    const float* x       = (const float*)d_in[0];
    // d_in[1] = mask: ignored (causal mask recomputed analytically)
    const float* cosb    = (const float*)d_in[2];
    const float* sinb    = (const float*)d_in[3];
    const float* Wq      = (const float*)d_in[4];
    const float* Wk      = (const float*)d_in[5];
    const float* Wv      = (const float*)d_in[6];
    const float* Wo      = (const float*)d_in[7];
    const float* q_scale = (const float*)d_in[8];
    const float* k_scale = (const float*)d_in[9];

    float* out   = (float*)d_out;                 // (2,2048,2048)
    float* k_out = out + 8388608;                 // (2,8,2048,64)
    float* v_out = k_out + 2097152;               // (2,8,2048,64)

    // one-time: allow 128 KB dynamic LDS for the 8-phase GEMM
    static bool attr_done = false;
    if (!attr_done) {
        hipFuncSetAttribute((const void*)gemm256_bt,
                            hipFuncAttributeMaxDynamicSharedMemorySize, 131072);
        attr_done = true;
    }

    char* ws = (char*)d_ws;
    size_t off = 0;
    auto alloc = [&](size_t bytes) {
        char* p = ws + off; off += (bytes + 255) & ~(size_t)255; return p;
    };
    unsigned short* x_bf   = (unsigned short*)alloc(4096ull * 2048 * 2);   // 16 MB
    unsigned short* Wqkvt  = (unsigned short*)alloc(3072ull * 2048 * 2);   // 12 MB
    unsigned short* Wot    = (unsigned short*)alloc(2048ull * 2048 * 2);   //  8 MB
    unsigned short* qkv    = (unsigned short*)alloc(4096ull * 3072 * 2);   // 24 MB
    unsigned short* q_attn = (unsigned short*)alloc(4096ull * 2048 * 2);   // 16 MB
    unsigned short* k_attn = (unsigned short*)alloc(2048ull * 2048 * 2);   //  4 MB
    unsigned short* vt     = (unsigned short*)alloc(2097152ull * 2);       //  4 MB
    unsigned short* ctx    = (unsigned short*)alloc(4096ull * 2048 * 2);   // 16 MB

    cast_x_kernel<<<8192, 256, 0, stream>>>(x, x_bf, 8388608);
    castT_kernel<<<1024, 256, 0, stream>>>(Wq, Wqkvt, 2048);
    castT_kernel<<<256, 256, 0, stream>>>(Wk, Wqkvt + 2048ull * 2048, 512);
    castT_kernel<<<256, 256, 0, stream>>>(Wv, Wqkvt + 2560ull * 2048, 512);
    castT_kernel<<<1024, 256, 0, stream>>>(Wo, Wot, 2048);

    // qkv = x @ [Wq|Wk|Wv]  (bf16 out)
    gemm256_bt<<<dim3(12, 16), 512, 131072, stream>>>(x_bf, Wqkvt, nullptr, qkv, 4096, 3072, 2048);

    rmsrope_kernel<<<49152, 256, 0, stream>>>(qkv, cosb, sinb, q_scale, k_scale,
                                              q_attn, k_attn, k_out, v_out);
    vtrans_kernel<<<512, 256, 0, stream>>>(qkv, vt);

    attn_kernel<<<1024, 256, 0, stream>>>(q_attn, k_attn, vt, ctx);

    // out = ctx @ Wo  (fp32 out)
    gemm256_bt<<<dim3(8, 16), 512, 131072, stream>>>(ctx, Wot, out, nullptr, 4096, 2048, 2048);
}

// Round 8
// 361.369 us; speedup vs baseline: 1.2738x; 1.0964x over previous
//
#include <hip/hip_runtime.h>

typedef __bf16 bf16_t;
typedef bf16_t bf16x8 __attribute__((ext_vector_type(8)));
typedef float f32x4 __attribute__((ext_vector_type(4)));

#define MFMA16(a, b, c) __builtin_amdgcn_mfma_f32_16x16x32_bf16(a, b, c, 0, 0, 0)

__device__ __forceinline__ unsigned short f2bf(float f) {
    union { float f; unsigned u; } v; v.f = f;
    unsigned r = v.u + 0x7FFFu + ((v.u >> 16) & 1u);  // RNE
    return (unsigned short)(r >> 16);
}
__device__ __forceinline__ float bf2f(unsigned short h) {
    union { unsigned u; float f; } v; v.u = ((unsigned)h) << 16;
    return v.f;
}
__device__ __forceinline__ unsigned short to_bf(float f) {
    bf16_t b = (bf16_t)f;                 // gfx950 native v_cvt (RNE)
    return __builtin_bit_cast(unsigned short, b);
}

// async global->LDS, 16B per lane; LDS dst is wave-uniform base + lane*16,
// global src address is per-lane.
__device__ __forceinline__ void gll16(const unsigned short* g, unsigned short* l) {
    __builtin_amdgcn_global_load_lds(
        (const __attribute__((address_space(1))) unsigned int*)g,
        (__attribute__((address_space(3))) unsigned int*)l, 16, 0, 0);
}

// ---------------- cast kernels ----------------
__global__ __launch_bounds__(256) void cast_x_kernel(const float* __restrict__ src,
                                                     unsigned short* __restrict__ dst, int n) {
    int i = (blockIdx.x * 256 + threadIdx.x) * 4;
    if (i >= n) return;
    float4 v = *(const float4*)&src[i];
    union { unsigned short e[4]; uint2 u; } p;
    p.e[0] = f2bf(v.x); p.e[1] = f2bf(v.y); p.e[2] = f2bf(v.z); p.e[3] = f2bf(v.w);
    *(uint2*)&dst[i] = p.u;
}

// All four weight transposes in ONE launch (saves 3 kernel launches).
// src is K x N row-major fp32 (K=2048); dst is N x K row-major bf16 (B^T).
__global__ __launch_bounds__(256) void castT_all_kernel(
    const float* __restrict__ Wq, const float* __restrict__ Wk,
    const float* __restrict__ Wv, const float* __restrict__ Wo,
    unsigned short* __restrict__ Wqkvt, unsigned short* __restrict__ Wot)
{
    __shared__ __align__(16) unsigned short sT[64 * 68];
    int idx = blockIdx.x;            // 2560 = 1024 Wq | 256 Wk | 256 Wv | 1024 Wo
    const float* src; unsigned short* dst; int N; int loc;
    if (idx < 1024)      { src = Wq; dst = Wqkvt;                    N = 2048; loc = idx; }
    else if (idx < 1280) { src = Wk; dst = Wqkvt + 2048ull * 2048;   N = 512;  loc = idx - 1024; }
    else if (idx < 1536) { src = Wv; dst = Wqkvt + 2560ull * 2048;   N = 512;  loc = idx - 1280; }
    else                 { src = Wo; dst = Wot;                      N = 2048; loc = idx - 1536; }
    int nt = loc >> 5;               // K/64 == 32 (K fixed at 2048)
    int kt = loc & 31;
    int k0 = kt * 64, n0 = nt * 64;
    int t = threadIdx.x;
#pragma unroll
    for (int c = t; c < 1024; c += 256) {
        int r = c >> 4, c4 = c & 15;
        float4 v = *(const float4*)&src[(size_t)(k0 + r) * N + n0 + c4 * 4];
        union { unsigned short e[4]; uint2 u; } p;
        p.e[0] = f2bf(v.x); p.e[1] = f2bf(v.y); p.e[2] = f2bf(v.z); p.e[3] = f2bf(v.w);
        *(uint2*)&sT[r * 68 + c4 * 4] = p.u;   // sT[k-row][n-col]
    }
    __syncthreads();
#pragma unroll
    for (int c = t; c < 512; c += 256) {
        int n = c >> 3, cb = c & 7;
        union { unsigned short e[8]; uint4 v; } u;
#pragma unroll
        for (int j = 0; j < 8; ++j) u.e[j] = sT[(cb * 8 + j) * 68 + n];
        *(uint4*)&dst[(size_t)(n0 + n) * 2048 + k0 + cb * 8] = u.v;
    }
}

// ---------------- GEMM: 256x256 tile, 8-phase counted-vmcnt schedule ----------
// (unchanged from R7 — verified passing). See schedule comment table there.
__global__ __launch_bounds__(512) void gemm256_bt(
    const unsigned short* __restrict__ A,
    const unsigned short* __restrict__ Bt,
    float* __restrict__ Cf, unsigned short* __restrict__ Cb,
    int M, int N, int K)
{
    extern __shared__ unsigned short lds[];   // [2][A 16384 | B 16384] ushorts = 131072 B
    const int KT = K >> 6;
    const int NIT = KT >> 1;

    int tid = threadIdx.x;
    int lane = tid & 63, w = tid >> 6;
    int wmi = w >> 2, wni = w & 3;
    int lo = lane & 15, quad = lane >> 4;
    int m0 = blockIdx.y * 256, n0 = blockIdx.x * 256;

    int rsub = lane >> 3;
    int csw  = ((lane & 7) ^ rsub) << 3;

    f32x4 acc[8][4];
#pragma unroll
    for (int i = 0; i < 8; ++i)
#pragma unroll
        for (int j = 0; j < 4; ++j) acc[i][j] = (f32x4){0.f, 0.f, 0.f, 0.f};

    auto stA = [&](int buf, int mp, int T) {
#pragma unroll
        for (int j = 0; j < 2; ++j) {
            int rr = (w * 2 + j) * 8 + rsub;
            gll16(A + (size_t)(m0 + mp * 128 + rr) * K + T * 64 + csw,
                  lds + buf * 32768 + mp * 8192 + (w * 2 + j) * 512);
        }
    };
    auto stB = [&](int buf, int np, int T) {
#pragma unroll
        for (int j = 0; j < 2; ++j) {
            int rr = (w * 2 + j) * 8 + rsub;
            gll16(Bt + (size_t)(n0 + np * 128 + rr) * K + T * 64 + csw,
                  lds + buf * 32768 + 16384 + np * 8192 + (w * 2 + j) * 512);
        }
    };

    auto phase = [&](int buf, int mp, int np, auto stage, bool drain) {
        bf16x8 a[4][2], b2[2][2];
#pragma unroll
        for (int mf = 0; mf < 4; ++mf)
#pragma unroll
            for (int k2 = 0; k2 < 2; ++k2) {
                int r = mp * 128 + wmi * 64 + mf * 16 + lo;
                int u = quad + k2 * 4;
                a[mf][k2] = *(const bf16x8*)&lds[buf * 32768 + r * 64 + ((u ^ (lo & 7)) << 3)];
            }
#pragma unroll
        for (int nf = 0; nf < 2; ++nf)
#pragma unroll
            for (int k2 = 0; k2 < 2; ++k2) {
                int r = np * 128 + wni * 32 + nf * 16 + lo;
                int u = quad + k2 * 4;
                b2[nf][k2] = *(const bf16x8*)&lds[buf * 32768 + 16384 + r * 64 + ((u ^ (lo & 7)) << 3)];
            }
        stage();
        __builtin_amdgcn_s_barrier();
        __builtin_amdgcn_sched_barrier(0);
        __builtin_amdgcn_s_setprio(1);
#pragma unroll
        for (int mf = 0; mf < 4; ++mf)
#pragma unroll
            for (int nf = 0; nf < 2; ++nf) {
                f32x4 z = acc[mp * 4 + mf][np * 2 + nf];
                z = MFMA16(a[mf][0], b2[nf][0], z);
                z = MFMA16(a[mf][1], b2[nf][1], z);
                acc[mp * 4 + mf][np * 2 + nf] = z;
            }
        __builtin_amdgcn_s_setprio(0);
        if (drain) asm volatile("s_waitcnt vmcnt(0)" ::: "memory");
        else       asm volatile("s_waitcnt vmcnt(6)" ::: "memory");
        __builtin_amdgcn_s_barrier();
        __builtin_amdgcn_sched_barrier(0);
    };
    auto nop = [&] {};

    stA(0, 0, 0); stB(0, 0, 0); stA(0, 1, 0); stB(0, 1, 0);
    stA(1, 0, 1); stB(1, 0, 1);
    asm volatile("s_waitcnt vmcnt(4)" ::: "memory");
    __builtin_amdgcn_s_barrier();
    __builtin_amdgcn_sched_barrier(0);

    for (int i = 0; i < NIT - 1; ++i) {
        int T1 = 2 * i + 1, T2 = 2 * i + 2, T3 = 2 * i + 3;
        phase(0, 0, 0, [&] { stA(1, 1, T1); }, false);
        phase(0, 0, 1, [&] { stB(1, 1, T1); }, false);
        phase(0, 1, 0, [&] { stA(0, 0, T2); }, false);
        phase(0, 1, 1, [&] { stB(0, 0, T2); }, false);
        phase(1, 0, 0, [&] { stA(0, 1, T2); }, false);
        phase(1, 0, 1, [&] { stB(0, 1, T2); }, false);
        phase(1, 1, 0, [&] { stA(1, 0, T3); }, false);
        phase(1, 1, 1, [&] { stB(1, 0, T3); }, false);
    }
    {
        int T1 = KT - 1;
        phase(0, 0, 0, [&] { stA(1, 1, T1); }, false);
        phase(0, 0, 1, [&] { stB(1, 1, T1); }, true);
        phase(0, 1, 0, nop, false);
        phase(0, 1, 1, nop, false);
        phase(1, 0, 0, nop, false);
        phase(1, 0, 1, nop, false);
        phase(1, 1, 0, nop, false);
        phase(1, 1, 1, nop, false);
    }

#pragma unroll
    for (int mi = 0; mi < 8; ++mi) {
        int mp = mi >> 2, mf = mi & 3;
        int row_base = m0 + mp * 128 + wmi * 64 + mf * 16 + quad * 4;
#pragma unroll
        for (int ni = 0; ni < 4; ++ni) {
            int np = ni >> 1, nf = ni & 1;
            int col = n0 + np * 128 + wni * 32 + nf * 16 + lo;
#pragma unroll
            for (int r = 0; r < 4; ++r) {
                int row = row_base + r;
                if (Cf) Cf[(size_t)row * N + col] = acc[mi][ni][r];
                else    Cb[(size_t)row * N + col] = f2bf(acc[mi][ni][r]);
            }
        }
    }
}

// ---------------- GEMM: 256x128 tile, 4-phase counted-vmcnt schedule ----------
// For N=2048 shapes where 256x256 gives only 128 blocks (50% CU idle): this
// tile gives (16,16)=256 blocks = every CU busy. 8 waves (2M x 4N, 32 cols per
// wave). Per phase: 12 ds_read_b128 + stage + barrier + 16 MFMA + vmcnt +
// barrier (identical arithmetic shape to gemm256's phase). A double-buffered
// (2 x 32KB, buf = T&1); B TRIPLE-buffered (3 x 16KB, buf = T%3) so every
// stage->consume lag >= ~3 phases. Phases per iter (tiles 2i [p1,p2], 2i+1
// [p3,p4]; phase = (Abuf, Bbuf, mp)):
//   p1: stage A-u1(2i+1)->d1, B(2i+2)   [wait vmcnt(8)]
//   p2: stage A-u0(2i+2)->d0            [wait vmcnt(6)]
//   p3: stage A-u1(2i+2)->d0, B(2i+3)   [wait vmcnt(8)]
//   p4: stage A-u0(2i+3)->d1            [wait vmcnt(6)]
// Hazard windows verified: every region is written only in phases strictly
// after its last read (A-u(mp) of buf d is read only in the mp-phase of d's
// tile; B-buf T%3's previous content T-3 was last read 4+ phases earlier).
// Tail: stages for T>=KT clamp the ADDRESS (refetch tile T-KT, unused) but
// keep the original T's buffer, which is provably dead at that point.
__global__ __launch_bounds__(512) void gemm256x128_bt(
    const unsigned short* __restrict__ A,
    const unsigned short* __restrict__ Bt,
    float* __restrict__ Cf, unsigned short* __restrict__ Cb,
    int M, int N, int K)
{
    extern __shared__ unsigned short lds[];   // A: 2x16384 @0 | B: 3x8192 @32768 (ushorts) = 114688 B
    const int KT = K >> 6;
    const int NIT = KT >> 1;

    int tid = threadIdx.x;
    int lane = tid & 63, w = tid >> 6;
    int wmi = w >> 2, wni = w & 3;            // M-half, N-quarter (32 cols)
    int lo = lane & 15, quad = lane >> 4;
    int m0 = blockIdx.y * 256, n0 = blockIdx.x * 128;

    int rsub = lane >> 3;
    int csw  = ((lane & 7) ^ rsub) << 3;

    f32x4 acc[8][2];
#pragma unroll
    for (int i = 0; i < 8; ++i)
#pragma unroll
        for (int j = 0; j < 2; ++j) acc[i][j] = (f32x4){0.f, 0.f, 0.f, 0.f};

    auto stA = [&](int d, int u, int T) {
        int Tc = T >= KT ? T - KT : T;        // clamp address only
#pragma unroll
        for (int j = 0; j < 2; ++j) {
            int rr = u * 128 + (w * 2 + j) * 8 + rsub;
            gll16(A + (size_t)(m0 + rr) * K + Tc * 64 + csw,
                  lds + d * 16384 + u * 8192 + (w * 2 + j) * 512);
        }
    };
    auto stB = [&](int T) {
        int t3 = T % 3;                        // buffer from ORIGINAL index (dead buf in tail)
        int Tc = T >= KT ? T - KT : T;
#pragma unroll
        for (int j = 0; j < 2; ++j) {
            int rr = (w * 2 + j) * 8 + rsub;
            gll16(Bt + (size_t)(n0 + rr) * K + Tc * 64 + csw,
                  lds + 32768 + t3 * 8192 + (w * 2 + j) * 512);
        }
    };

    auto phase = [&](int d, int t3, int mp, auto stage, bool w8) {
        bf16x8 a[4][2], b2[2][2];
#pragma unroll
        for (int mf = 0; mf < 4; ++mf)
#pragma unroll
            for (int k2 = 0; k2 < 2; ++k2) {
                int r = mp * 128 + wmi * 64 + mf * 16 + lo;
                int u = quad + k2 * 4;
                a[mf][k2] = *(const bf16x8*)&lds[d * 16384 + r * 64 + ((u ^ (lo & 7)) << 3)];
            }
#pragma unroll
        for (int nf = 0; nf < 2; ++nf)
#pragma unroll
            for (int k2 = 0; k2 < 2; ++k2) {
                int r = wni * 32 + nf * 16 + lo;
                int u = quad + k2 * 4;
                b2[nf][k2] = *(const bf16x8*)&lds[32768 + t3 * 8192 + r * 64 + ((u ^ (lo & 7)) << 3)];
            }
        stage();
        __builtin_amdgcn_s_barrier();
        __builtin_amdgcn_sched_barrier(0);
        __builtin_amdgcn_s_setprio(1);
#pragma unroll
        for (int mf = 0; mf < 4; ++mf)
#pragma unroll
            for (int nf = 0; nf < 2; ++nf) {
                f32x4 z = acc[mp * 4 + mf][nf];
                z = MFMA16(a[mf][0], b2[nf][0], z);
                z = MFMA16(a[mf][1], b2[nf][1], z);
                acc[mp * 4 + mf][nf] = z;
            }
        __builtin_amdgcn_s_setprio(0);
        if (w8) asm volatile("s_waitcnt vmcnt(8)" ::: "memory");
        else    asm volatile("s_waitcnt vmcnt(6)" ::: "memory");
        __builtin_amdgcn_s_barrier();
        __builtin_amdgcn_sched_barrier(0);
    };

    // prologue: A(0) both units, B(0), A-u0(1), B(1); first 3 units must land
    stA(0, 0, 0); stA(0, 1, 0); stB(0);
    stA(1, 0, 1); stB(1);
    asm volatile("s_waitcnt vmcnt(4)" ::: "memory");
    __builtin_amdgcn_s_barrier();
    __builtin_amdgcn_sched_barrier(0);

    for (int i = 0; i < NIT; ++i) {
        int T0 = 2 * i, T1 = 2 * i + 1, T2 = 2 * i + 2, T3 = 2 * i + 3;
        int b0 = T0 % 3, b1 = T1 % 3;
        phase(0, b0, 0, [&] { stA(1, 1, T1); stB(T2); }, true);
        phase(0, b0, 1, [&] { stA(0, 0, T2); },          false);
        phase(1, b1, 0, [&] { stA(0, 1, T2); stB(T3); }, true);
        phase(1, b1, 1, [&] { stA(1, 0, T3); },          false);
    }

#pragma unroll
    for (int mi = 0; mi < 8; ++mi) {
        int mp = mi >> 2, mf = mi & 3;
        int row_base = m0 + mp * 128 + wmi * 64 + mf * 16 + quad * 4;
#pragma unroll
        for (int nf = 0; nf < 2; ++nf) {
            int col = n0 + wni * 32 + nf * 16 + lo;
#pragma unroll
            for (int r = 0; r < 4; ++r) {
                int row = row_base + r;
                if (Cf) Cf[(size_t)row * N + col] = acc[mi][nf][r];
                else    Cb[(size_t)row * N + col] = f2bf(acc[mi][nf][r]);
            }
        }
    }
}

// ---------------- RMSNorm + RoPE (+ scatter to outputs) ----------------
// qkv: (B*S, 3072) bf16 rows = [q 2048 | k 512 | v 512]
__global__ __launch_bounds__(256) void rmsrope_kernel(
    const unsigned short* __restrict__ qkv,
    const float* __restrict__ cosb, const float* __restrict__ sinb,
    const float* __restrict__ q_scale, const float* __restrict__ k_scale,
    unsigned short* __restrict__ q_attn, unsigned short* __restrict__ k_attn,
    float* __restrict__ k_out, float* __restrict__ v_out)
{
    int wid = blockIdx.x * 4 + (threadIdx.x >> 6);   // one wave per 64-elem row
    int lane = threadIdx.x & 63;
    int t = wid % 48;          // 0..31 q-head, 32..39 k-group, 40..47 v-group
    int bs = wid / 48;         // 0..4095
    int b = bs >> 11, s = bs & 2047;

    if (t >= 40) {             // v: straight copy to output (b,g,s,d) fp32
        int g = t - 40;
        float val = bf2f(qkv[(size_t)bs * 3072 + 2560 + g * 64 + lane]);
        v_out[(size_t)((b * 8 + g) * 2048 + s) * 64 + lane] = val;
        return;
    }
    bool is_q = (t < 32);
    int col = is_q ? (t * 64) : (2048 + (t - 32) * 64);
    float val = bf2f(qkv[(size_t)bs * 3072 + col + lane]);
    float ss = val * val;
#pragma unroll
    for (int m = 1; m < 64; m <<= 1) ss += __shfl_xor(ss, m);
    float rs = rsqrtf(ss * (1.0f / 64.0f) + 1e-6f);
    float scl = is_q ? q_scale[lane] : k_scale[lane];
    float xn = val * rs * scl;
    float other = __shfl_xor(xn, 32);
    float rot = (lane < 32) ? -other : other;     // [-x2, x1]
    float o = xn * cosb[s * 64 + lane] + rot * sinb[s * 64 + lane];
    if (is_q) {
        // fold 1/sqrt(D)=0.125 and log2(e) into q (attention works in exp2 domain)
        q_attn[(size_t)((b * 32 + t) * 2048 + s) * 64 + lane] = to_bf(o * (0.125f * 1.44269504f));
    } else {
        int g = t - 32;
        size_t idx = (size_t)((b * 8 + g) * 2048 + s) * 64 + lane;
        k_attn[idx] = to_bf(o);
        k_out[idx] = o;
    }
}

// ---------------- V transpose: qkv v-cols -> vt (b,g,d,s) bf16 ----------------
__global__ __launch_bounds__(256) void vtrans_kernel(
    const unsigned short* __restrict__ qkv, unsigned short* __restrict__ vt)
{
    __shared__ __align__(16) unsigned short sT[64 * 68];
    int idx = blockIdx.x;            // B*G*32 = 512
    int st = idx & 31, g = (idx >> 5) & 7, b = idx >> 8;
    int tid = threadIdx.x;
#pragma unroll
    for (int c = tid; c < 512; c += 256) {
        int r = c >> 3, cb = c & 7;
        *(uint4*)&sT[r * 68 + cb * 8] =
            *(const uint4*)&qkv[(size_t)(b * 2048 + st * 64 + r) * 3072 + 2560 + g * 64 + cb * 8];
    }
    __syncthreads();
#pragma unroll
    for (int c = tid; c < 512; c += 256) {
        int d = c >> 3, cb = c & 7;
        union { unsigned short e[8]; uint4 v; } u;
#pragma unroll
        for (int j = 0; j < 8; ++j) u.e[j] = sT[(cb * 8 + j) * 68 + d];
        *(uint4*)&vt[((size_t)(b * 8 + g) * 64 + d) * 2048 + st * 64 + cb * 8] = u.v;
    }
}

// ---------------- flash attention, causal, GQA (R6 structure, unchanged) ----
__global__ __launch_bounds__(256, 2) void attn_kernel(
    const unsigned short* __restrict__ q_attn,   // (b,h,s,d) bf16, pre-scaled (log2 domain)
    const unsigned short* __restrict__ k_attn,   // (b,g,s,d) bf16 post-rope
    const unsigned short* __restrict__ vt,       // (b,g,d,s) bf16
    unsigned short* __restrict__ ctx)            // (b,s,h*d) bf16
{
    __shared__ __align__(16) unsigned short sK[2][4096];   // 16 KB (2 x 64x64 bf16)
    __shared__ __align__(16) unsigned short sV[2][4096];   // 16 KB
    __shared__ __align__(16) unsigned short sP[4][16 * 68];// 8.5 KB (wave-private)

    int w = threadIdx.x >> 6;        // wave in block = head-in-group, 0..3
    int lane = threadIdx.x & 63;

    int g = blockIdx.x & 7;          // XCD swizzle: (b,g) working set pinned per XCD
    int ord = blockIdx.x >> 3;       // 0..127
    int b = ord & 1;
    int qt = 63 - (ord >> 1);        // 63..0: longest tasks dispatched first
    int h = g * 4 + w;

    int lo = lane & 15, quad = lane >> 4;
    unsigned short* sPw = sP[w];

    const unsigned short* Qb = q_attn + (size_t)(b * 32 + h) * 2048 * 64;
    const unsigned short* Kb = k_attn + (size_t)(b * 8 + g) * 2048 * 64;
    const unsigned short* Vb = vt + (size_t)(b * 8 + g) * 64 * 2048;

    int nt = (qt >> 1) + 1;          // kv tiles 0..nt-1 (tile = 64 kv)

    int rsub = lane >> 3;                  // 0..7 (== row & 7 within chunk)
    int csw  = ((lane & 7) ^ rsub) << 3;   // ushort units

    auto STAGE = [&](int buf, int kt) {
#pragma unroll
        for (int i = 0; i < 2; ++i) {
            int c = w + i * 4;             // this wave's chunks: w, w+4
            gll16(Kb + (size_t)(kt * 64 + c * 8 + rsub) * 64 + csw, &sK[buf][c * 512]);
            gll16(Vb + (size_t)(c * 8 + rsub) * 2048 + kt * 64 + csw, &sV[buf][c * 512]);
        }
    };

    const bf16_t one = (bf16_t)1.0f;
    const bf16x8 vone = {one, one, one, one, one, one, one, one};

    bf16x8 qf[2][2];
#pragma unroll
    for (int mt = 0; mt < 2; ++mt)
#pragma unroll
        for (int h2 = 0; h2 < 2; ++h2)
            qf[mt][h2] = *(const bf16x8*)&Qb[(size_t)(qt * 32 + mt * 16 + lo) * 64 + h2 * 32 + quad * 8];

    f32x4 o_acc[2][4];
    f32x4 l_acc[2];
#pragma unroll
    for (int mt = 0; mt < 2; ++mt) {
        l_acc[mt] = (f32x4){0.f, 0.f, 0.f, 0.f};
#pragma unroll
        for (int j = 0; j < 4; ++j) o_acc[mt][j] = (f32x4){0.f, 0.f, 0.f, 0.f};
    }

    STAGE(0, 0);
    __syncthreads();                 // drains vmcnt(0): buffer 0 complete

    int cur = 0;
    for (int kt = 0; kt < nt; ++kt) {
        if (kt + 1 < nt) STAGE(cur ^ 1, kt + 1);   // issue-early, in flight during compute

        const char* sKc = (const char*)sK[cur];
        const char* sVc = (const char*)sV[cur];
        bool domask = (kt == nt - 1);

#pragma unroll
        for (int mt = 0; mt < 2; ++mt) {
            f32x4 sc[4];
            __builtin_amdgcn_s_setprio(1);
#pragma unroll
            for (int ct = 0; ct < 4; ++ct) {
                int krow = ct * 16 + lo;
                int rsw = (krow & 7) << 4;
                bf16x8 kf0 = *(const bf16x8*)(sKc + (krow << 7) + (((quad << 4)) ^ rsw));
                bf16x8 kf1 = *(const bf16x8*)(sKc + (krow << 7) + (((1 << 6) | (quad << 4)) ^ rsw));
                f32x4 z = (f32x4){0.f, 0.f, 0.f, 0.f};
                z = MFMA16(qf[mt][0], kf0, z);
                z = MFMA16(qf[mt][1], kf1, z);
                sc[ct] = z;
            }
            __builtin_amdgcn_s_setprio(0);
            if (domask) {
                int qrow0 = qt * 32 + mt * 16 + quad * 4;
#pragma unroll
                for (int ct = 0; ct < 4; ++ct)
#pragma unroll
                    for (int r = 0; r < 4; ++r)
                        if (kt * 64 + ct * 16 + lo > qrow0 + r) sc[ct][r] = -INFINITY;
            }
#pragma unroll
            for (int ct = 0; ct < 4; ++ct)
#pragma unroll
                for (int r = 0; r < 4; ++r)
                    sc[ct][r] = __builtin_amdgcn_exp2f(sc[ct][r]);

#pragma unroll
            for (int ct = 0; ct < 4; ++ct)
#pragma unroll
                for (int r = 0; r < 4; ++r)
                    sPw[(quad * 4 + r) * 68 + ct * 16 + lo] = to_bf(sc[ct][r]);

            bf16x8 pf0 = *(const bf16x8*)&sPw[lo * 68 + quad * 8];
            bf16x8 pf1 = *(const bf16x8*)&sPw[lo * 68 + 32 + quad * 8];

            __builtin_amdgcn_s_setprio(1);
            l_acc[mt] = MFMA16(pf0, vone, l_acc[mt]);
            l_acc[mt] = MFMA16(pf1, vone, l_acc[mt]);

#pragma unroll
            for (int nt2 = 0; nt2 < 4; ++nt2) {
                int vrow = nt2 * 16 + lo;
                int rsw = (vrow & 7) << 4;
                bf16x8 vf0 = *(const bf16x8*)(sVc + (vrow << 7) + (((quad << 4)) ^ rsw));
                bf16x8 vf1 = *(const bf16x8*)(sVc + (vrow << 7) + (((1 << 6) | (quad << 4)) ^ rsw));
                f32x4 oo = o_acc[mt][nt2];
                oo = MFMA16(pf0, vf0, oo);
                oo = MFMA16(pf1, vf1, oo);
                o_acc[mt][nt2] = oo;
            }
            __builtin_amdgcn_s_setprio(0);
        }

        __syncthreads();
        cur ^= 1;
    }

#pragma unroll
    for (int mt = 0; mt < 2; ++mt)
#pragma unroll
        for (int r = 0; r < 4; ++r) {
            float inv = 1.0f / l_acc[mt][r];
            int row = qt * 32 + mt * 16 + quad * 4 + r;
#pragma unroll
            for (int nt2 = 0; nt2 < 4; ++nt2) {
                size_t oi = ((size_t)(b * 2048 + row)) * 2048 + h * 64 + nt2 * 16 + lo;
                ctx[oi] = to_bf(o_acc[mt][nt2][r] * inv);
            }
        }
}

// ---------------- launch ----------------
extern "C" void kernel_launch(void* const* d_in, const int* in_sizes, int n_in,
                              void* d_out, int out_size, void* d_ws, size_t ws_size,
                              hipStream_t stream)
{
    (void)in_sizes; (void)n_in; (void)out_size; (void)ws_size;
    const float* x       = (const float*)d_in[0];
    // d_in[1] = mask: ignored (causal mask recomputed analytically)
    const float* cosb    = (const float*)d_in[2];
    const float* sinb    = (const float*)d_in[3];
    const float* Wq      = (const float*)d_in[4];
    const float* Wk      = (const float*)d_in[5];
    const float* Wv      = (const float*)d_in[6];
    const float* Wo      = (const float*)d_in[7];
    const float* q_scale = (const float*)d_in[8];
    const float* k_scale = (const float*)d_in[9];

    float* out   = (float*)d_out;                 // (2,2048,2048)
    float* k_out = out + 8388608;                 // (2,8,2048,64)
    float* v_out = k_out + 2097152;               // (2,8,2048,64)

    // one-time: allow big dynamic LDS for the pipelined GEMMs
    static bool attr_done = false;
    if (!attr_done) {
        hipFuncSetAttribute((const void*)gemm256_bt,
                            hipFuncAttributeMaxDynamicSharedMemorySize, 131072);
        hipFuncSetAttribute((const void*)gemm256x128_bt,
                            hipFuncAttributeMaxDynamicSharedMemorySize, 114688);
        attr_done = true;
    }

    char* ws = (char*)d_ws;
    size_t off = 0;
    auto alloc = [&](size_t bytes) {
        char* p = ws + off; off += (bytes + 255) & ~(size_t)255; return p;
    };
    unsigned short* x_bf   = (unsigned short*)alloc(4096ull * 2048 * 2);   // 16 MB
    unsigned short* Wqkvt  = (unsigned short*)alloc(3072ull * 2048 * 2);   // 12 MB
    unsigned short* Wot    = (unsigned short*)alloc(2048ull * 2048 * 2);   //  8 MB
    unsigned short* qkv    = (unsigned short*)alloc(4096ull * 3072 * 2);   // 24 MB
    unsigned short* q_attn = (unsigned short*)alloc(4096ull * 2048 * 2);   // 16 MB
    unsigned short* k_attn = (unsigned short*)alloc(2048ull * 2048 * 2);   //  4 MB
    unsigned short* vt     = (unsigned short*)alloc(2097152ull * 2);       //  4 MB
    unsigned short* ctx    = (unsigned short*)alloc(4096ull * 2048 * 2);   // 16 MB

    cast_x_kernel<<<8192, 256, 0, stream>>>(x, x_bf, 8388608);
    castT_all_kernel<<<2560, 256, 0, stream>>>(Wq, Wk, Wv, Wo, Wqkvt, Wot);

    // qkv = x @ [Wq|Wk|Wv]  (bf16 out)
    gemm256_bt<<<dim3(12, 16), 512, 131072, stream>>>(x_bf, Wqkvt, nullptr, qkv, 4096, 3072, 2048);

    rmsrope_kernel<<<49152, 256, 0, stream>>>(qkv, cosb, sinb, q_scale, k_scale,
                                              q_attn, k_attn, k_out, v_out);
    vtrans_kernel<<<512, 256, 0, stream>>>(qkv, vt);

    attn_kernel<<<1024, 256, 0, stream>>>(q_attn, k_attn, vt, ctx);

    // out = ctx @ Wo  (fp32 out) — 256x128 tiles: 256 blocks, every CU busy
    gemm256x128_bt<<<dim3(16, 16), 512, 114688, stream>>>(ctx, Wot, out, nullptr, 4096, 2048, 2048);
}